// Round 3
// baseline (759.814 us; speedup 1.0000x reference)
//
#include <hip/hip_runtime.h>
#include <hip/hip_bf16.h>
#include <cstdint>

namespace {

constexpr int BS   = 2048;
constexpr int DIM  = 256;
constexpr int K    = 3000;
constexpr int K4   = K / 4;        // 750
constexpr int KP   = 3008;         // padded row stride (bf16 matrix)
constexpr int KP4  = KP / 4;       // 752
constexpr int QL   = 3840;
constexpr int NTOT = QL + BS;      // 5888
constexpr int N2   = 2 * BS;       // 4096
constexpr int ROWS_PER_BLK = 23;   // 5888 / 256
constexpr float TEMP = 0.2f;
constexpr float INV_EPS = 20.0f;
constexpr float KF = 3000.0f;

// ws layout (float indices)
constexpr size_t M_FLOATS = (size_t)NTOT * KP / 2;       // bf16 matrix
constexpr size_t OFF_M    = 0;
constexpr size_t OFF_S    = OFF_M + M_FLOATS;            // 3*KP (S1,S2,S3)
constexpr size_t OFF_ACC  = OFF_S + 3 * KP;              // 8
constexpr size_t OFF_HQ   = OFF_ACC + 8;                 // N2 ints
constexpr size_t OFF_NQ   = OFF_HQ + N2;                 // N2*6 ints
constexpr size_t OFF_CVT  = ((OFF_NQ + (size_t)N2 * 6 + 15) / 16) * 16;
constexpr size_t CVT_ELEM = (size_t)(2 * QL + K) * DIM;  // ushorts
constexpr size_t CVT_FL   = CVT_ELEM / 2;
constexpr size_t OFF_CVT_HI = OFF_CVT;
constexpr size_t OFF_CVT_LO = OFF_CVT_HI + CVT_FL;
constexpr size_t OFF_OUTC   = OFF_CVT_HI;                // reuse after GEMMs

using bf16x8 = __attribute__((ext_vector_type(8))) short;
using f32x4  = __attribute__((ext_vector_type(4))) float;

__device__ __forceinline__ float wave_sum(float v) {
#pragma unroll
  for (int off = 32; off > 0; off >>= 1) v += __shfl_down(v, off, 64);
  return v;
}
__device__ __forceinline__ float wave_max(float v) {
#pragma unroll
  for (int off = 32; off > 0; off >>= 1) v = fmaxf(v, __shfl_down(v, off, 64));
  return v;
}
__device__ __forceinline__ unsigned long long wave_maxu64(unsigned long long v) {
#pragma unroll
  for (int off = 32; off > 0; off >>= 1) {
    unsigned long long o = __shfl_down(v, off, 64);
    v = (o > v) ? o : v;
  }
  return v;
}
__device__ __forceinline__ unsigned int fmono(float f) {
  unsigned int u = __float_as_uint(f);
  return (u & 0x80000000u) ? ~u : (u | 0x80000000u);
}
__device__ __forceinline__ float bf2f(short s) {
  return __uint_as_float(((unsigned int)(unsigned short)s) << 16);
}
__device__ __forceinline__ ushort f2bf(float f) {
  __hip_bfloat16 b = __float2bfloat16(f);
  return *reinterpret_cast<ushort*>(&b);
}

// -------- split f32 -> (hi, lo) bf16 --------
__global__ __launch_bounds__(256) void k_convert(
    const float* __restrict__ x, ushort* __restrict__ hi, ushort* __restrict__ lo, int n4) {
  int i = blockIdx.x * 256 + threadIdx.x;
  if (i >= n4) return;
  float4 v = reinterpret_cast<const float4*>(x)[i];
  ushort4 h, l;
  h.x = f2bf(v.x); l.x = f2bf(v.x - bf2f((short)h.x));
  h.y = f2bf(v.y); l.y = f2bf(v.y - bf2f((short)h.y));
  h.z = f2bf(v.z); l.z = f2bf(v.z - bf2f((short)h.z));
  h.w = f2bf(v.w); l.w = f2bf(v.w - bf2f((short)h.w));
  reinterpret_cast<ushort4*>(hi)[i] = h;
  reinterpret_cast<ushort4*>(lo)[i] = l;
}

// -------- MFMA GEMM: M[m][n] = bf16(exp(dot/EPS)) (queue rows); S += colsum --------
__global__ __launch_bounds__(256) void k_gemm_split(
    const ushort* __restrict__ Ahi_g, const ushort* __restrict__ Alo_g,  // [3840][256]
    const ushort* __restrict__ Bhi_g, const ushort* __restrict__ Blo_g,  // [3000][256]
    ushort* __restrict__ M, float* __restrict__ S) {
  __shared__ ushort Ah[128][40], Al[128][40], Bh[128][40], Bl[128][40];
  const int tid  = threadIdx.x;
  const int bn0  = blockIdx.x * 128;  // class dim
  const int bm0  = blockIdx.y * 128;  // queue row
  const int wid  = tid >> 6, lane = tid & 63;
  const int wm0  = (wid >> 1) * 64, wn0 = (wid & 1) * 64;
  const int ln15 = lane & 15, lq = lane >> 4;
  const int lr   = tid >> 2;
  const int lc   = (tid & 3) * 8;

  f32x4 acc[4][4] = {};

  for (int kk = 0; kk < DIM; kk += 32) {
#pragma unroll
    for (int p = 0; p < 2; ++p) {
      int row = p * 64 + lr;
      size_t ga = (size_t)(bm0 + row) * DIM + kk + lc;
      int brow = bn0 + row; if (brow >= K) brow = K - 1;
      size_t gb = (size_t)brow * DIM + kk + lc;
      *reinterpret_cast<bf16x8*>(&Ah[row][lc]) = *reinterpret_cast<const bf16x8*>(&Ahi_g[ga]);
      *reinterpret_cast<bf16x8*>(&Al[row][lc]) = *reinterpret_cast<const bf16x8*>(&Alo_g[ga]);
      *reinterpret_cast<bf16x8*>(&Bh[row][lc]) = *reinterpret_cast<const bf16x8*>(&Bhi_g[gb]);
      *reinterpret_cast<bf16x8*>(&Bl[row][lc]) = *reinterpret_cast<const bf16x8*>(&Blo_g[gb]);
    }
    __syncthreads();
    bf16x8 ah[4], al[4], bh[4], bl[4];
#pragma unroll
    for (int i = 0; i < 4; ++i) {
      ah[i] = *reinterpret_cast<const bf16x8*>(&Ah[wm0 + i * 16 + ln15][lq * 8]);
      al[i] = *reinterpret_cast<const bf16x8*>(&Al[wm0 + i * 16 + ln15][lq * 8]);
      bh[i] = *reinterpret_cast<const bf16x8*>(&Bh[wn0 + i * 16 + ln15][lq * 8]);
      bl[i] = *reinterpret_cast<const bf16x8*>(&Bl[wn0 + i * 16 + ln15][lq * 8]);
    }
#pragma unroll
    for (int i = 0; i < 4; ++i)
#pragma unroll
      for (int j = 0; j < 4; ++j) {
        acc[i][j] = __builtin_amdgcn_mfma_f32_16x16x32_bf16(ah[i], bh[j], acc[i][j], 0, 0, 0);
        acc[i][j] = __builtin_amdgcn_mfma_f32_16x16x32_bf16(ah[i], bl[j], acc[i][j], 0, 0, 0);
        acc[i][j] = __builtin_amdgcn_mfma_f32_16x16x32_bf16(al[i], bh[j], acc[i][j], 0, 0, 0);
      }
    __syncthreads();
  }

#pragma unroll
  for (int j = 0; j < 4; ++j) {
    int col = bn0 + wn0 + j * 16 + ln15;
    bool valid = col < K;
    bool inmat = col < KP;
    float csum = 0.f;
#pragma unroll
    for (int i = 0; i < 4; ++i) {
      int rowb = bm0 + wm0 + i * 16 + lq * 4;
#pragma unroll
      for (int r = 0; r < 4; ++r) {
        float q = valid ? expf(acc[i][j][r] * INV_EPS) : 0.f;
        if (inmat) M[(size_t)(rowb + r) * KP + col] = f2bf(q);
        csum += q;
      }
    }
    csum += __shfl_xor(csum, 16, 64);
    csum += __shfl_xor(csum, 32, 64);
    if (lane < 16 && valid) atomicAdd(&S[col], csum);
  }
}

// -------- sample rows: exp -> bf16 matrix rows + v0-colsum into S --------
__global__ __launch_bounds__(256) void k_initsample(
    const float* __restrict__ outCrop, ushort* __restrict__ M, float* __restrict__ S) {
  int k4 = blockIdx.x * 256 + threadIdx.x;
  if (k4 >= KP4) return;
  bool pad = k4 >= K4;
  int r0 = blockIdx.y * 32;
  float ax = 0.f, ay = 0.f, az = 0.f, aw = 0.f;
  for (int rr = 0; rr < 32; ++rr) {
    int row = r0 + rr;
    ushort4 w = make_ushort4(0, 0, 0, 0);
    if (!pad) {
      float4 x = reinterpret_cast<const float4*>(outCrop + (size_t)row * K)[k4];
      float ex = expf(x.x * INV_EPS), ey = expf(x.y * INV_EPS),
            ez = expf(x.z * INV_EPS), ew = expf(x.w * INV_EPS);
      ax += ex; ay += ey; az += ez; aw += ew;
      w.x = f2bf(ex); w.y = f2bf(ey); w.z = f2bf(ez); w.w = f2bf(ew);
    }
    reinterpret_cast<ushort4*>(M + (size_t)(QL + row) * KP)[k4] = w;
  }
  if (!pad) {
    atomicAdd(&S[k4 * 4 + 0], ax);
    atomicAdd(&S[k4 * 4 + 1], ay);
    atomicAdd(&S[k4 * 4 + 2], az);
    atomicAdd(&S[k4 * 4 + 3], aw);
  }
}

// -------- fused sinkhorn iteration: rows in LDS; rowsum->v; colsum*v -> S_out --------
__global__ __launch_bounds__(256) void k_sink_fused(
    const ushort* __restrict__ M, const float* __restrict__ S_in, float* __restrict__ S_out) {
  __shared__ ushort lds[ROWS_PER_BLK][KP] __attribute__((aligned(16)));
  __shared__ float red[ROWS_PER_BLK][4];
  __shared__ float vsh[ROWS_PER_BLK];
  const int tid = threadIdx.x;
  const int wid = tid >> 6, lane = tid & 63;
  const int row0 = blockIdx.x * ROWS_PER_BLK;

  // ---- stage 23 rows (contiguous 138368 B region) into LDS ----
  const bf16x8* gsrc = reinterpret_cast<const bf16x8*>(M + (size_t)row0 * KP);
  bf16x8* ldst = reinterpret_cast<bf16x8*>(&lds[0][0]);
  constexpr int NGRP = ROWS_PER_BLK * KP / 8;  // 8648
#pragma unroll 1
  for (int o = 0; o < 4; ++o) {
    bf16x8 b[8];
#pragma unroll
    for (int q = 0; q < 8; ++q) b[q] = gsrc[o * 2048 + q * 256 + tid];
#pragma unroll
    for (int q = 0; q < 8; ++q) ldst[o * 2048 + q * 256 + tid] = b[q];
  }
  {
    int i0 = 8192 + tid, i1 = 8448 + tid;
    bf16x8 b0, b1;
    bool v1 = i1 < NGRP;
    b0 = gsrc[i0];
    if (v1) b1 = gsrc[i1];
    ldst[i0] = b0;
    if (v1) ldst[i1] = b1;
  }
  __syncthreads();

  // ---- per-thread column ownership: group g1 = tid (always), g2 = tid+256 (tid<120) ----
  const int g1 = tid;
  const int g2 = tid + 256;
  const bool has2 = g2 < KP / 8;            // 376 groups
  const bool pad2 = has2 && (g2 == 375);    // columns 3000..3007
  float ua[8], ub[8];
  {
    float4 s0 = reinterpret_cast<const float4*>(S_in)[g1 * 2];
    float4 s1 = reinterpret_cast<const float4*>(S_in)[g1 * 2 + 1];
    ua[0] = 1.0f / (KF * s0.x); ua[1] = 1.0f / (KF * s0.y);
    ua[2] = 1.0f / (KF * s0.z); ua[3] = 1.0f / (KF * s0.w);
    ua[4] = 1.0f / (KF * s1.x); ua[5] = 1.0f / (KF * s1.y);
    ua[6] = 1.0f / (KF * s1.z); ua[7] = 1.0f / (KF * s1.w);
  }
  if (has2 && !pad2) {
    float4 s0 = reinterpret_cast<const float4*>(S_in)[g2 * 2];
    float4 s1 = reinterpret_cast<const float4*>(S_in)[g2 * 2 + 1];
    ub[0] = 1.0f / (KF * s0.x); ub[1] = 1.0f / (KF * s0.y);
    ub[2] = 1.0f / (KF * s0.z); ub[3] = 1.0f / (KF * s0.w);
    ub[4] = 1.0f / (KF * s1.x); ub[5] = 1.0f / (KF * s1.y);
    ub[6] = 1.0f / (KF * s1.z); ub[7] = 1.0f / (KF * s1.w);
  } else {
#pragma unroll
    for (int e = 0; e < 8; ++e) ub[e] = 0.f;
  }

  // ---- phase 1: row sums with u -> v ----
  float part[ROWS_PER_BLK];
#pragma unroll
  for (int r = 0; r < ROWS_PER_BLK; ++r) {
    bf16x8 a = *reinterpret_cast<const bf16x8*>(&lds[r][g1 * 8]);
    float s = 0.f;
#pragma unroll
    for (int e = 0; e < 8; ++e) s += bf2f(a[e]) * ua[e];
    if (has2) {
      bf16x8 c = *reinterpret_cast<const bf16x8*>(&lds[r][g2 * 8]);
#pragma unroll
      for (int e = 0; e < 8; ++e) s += bf2f(c[e]) * ub[e];
    }
    part[r] = s;
  }
#pragma unroll
  for (int r = 0; r < ROWS_PER_BLK; ++r) {
    float s = wave_sum(part[r]);
    if (lane == 0) red[r][wid] = s;
  }
  __syncthreads();
  if (tid < ROWS_PER_BLK)
    vsh[tid] = 1.0f / ((float)NTOT * (red[tid][0] + red[tid][1] + red[tid][2] + red[tid][3]));
  __syncthreads();

  // ---- phase 2: column sums weighted by v -> S_out atomics ----
  float c1[8], c2[8];
#pragma unroll
  for (int e = 0; e < 8; ++e) { c1[e] = 0.f; c2[e] = 0.f; }
#pragma unroll
  for (int r = 0; r < ROWS_PER_BLK; ++r) {
    float vr = vsh[r];
    bf16x8 a = *reinterpret_cast<const bf16x8*>(&lds[r][g1 * 8]);
#pragma unroll
    for (int e = 0; e < 8; ++e) c1[e] += bf2f(a[e]) * vr;
    if (has2) {
      bf16x8 c = *reinterpret_cast<const bf16x8*>(&lds[r][g2 * 8]);
#pragma unroll
      for (int e = 0; e < 8; ++e) c2[e] += bf2f(c[e]) * vr;
    }
  }
#pragma unroll
  for (int e = 0; e < 8; ++e) atomicAdd(&S_out[g1 * 8 + e], c1[e]);
  if (has2) {
#pragma unroll
    for (int e = 0; e < 8; ++e) atomicAdd(&S_out[g2 * 8 + e], c2[e]);
  }
}

// -------- per sample row: hard_q, neg_q, fused final-v, crop-1 cc term --------
__global__ __launch_bounds__(256) void k_stats(
    const float* __restrict__ outputAll, const float* __restrict__ S3,
    int crop, int* __restrict__ hardq, int* __restrict__ negq, float* __restrict__ accum) {
  __shared__ float skey[K];
  __shared__ unsigned long long ml[256][8];
  __shared__ unsigned long long sm4[4];
  __shared__ float red[4][4];
  const int tid = threadIdx.x;
  const int j = blockIdx.x;
  const float* orow = outputAll + (size_t)(crop * BS + j) * K;

  float svp = 0.f;
  for (int k4 = tid; k4 < K4; k4 += 256) {
    float4 o = reinterpret_cast<const float4*>(orow)[k4];
    float4 s = reinterpret_cast<const float4*>(S3)[k4];
    float4 kv;
    kv.x = expf(o.x * INV_EPS) / (KF * s.x);
    kv.y = expf(o.y * INV_EPS) / (KF * s.y);
    kv.z = expf(o.z * INV_EPS) / (KF * s.z);
    kv.w = expf(o.w * INV_EPS) / (KF * s.w);
    reinterpret_cast<float4*>(skey)[k4] = kv;
    svp += kv.x + kv.y + kv.z + kv.w;
  }
  svp = wave_sum(svp);
  if ((tid & 63) == 0) red[0][tid >> 6] = svp;
  __syncthreads();
  const float sv = red[0][0] + red[0][1] + red[0][2] + red[0][3];

  unsigned long long am = 0ull;
  for (int k = tid; k < K; k += 256) {
    unsigned long long p = ((unsigned long long)fmono(skey[k]) << 32) | (unsigned int)(~k);
    am = (p > am) ? p : am;
  }
  am = wave_maxu64(am);
  if ((tid & 63) == 0) sm4[tid >> 6] = am;

  unsigned long long best[8];
#pragma unroll
  for (int t = 0; t < 8; ++t) best[t] = ~0ull;
  for (int k = tid; k < K; k += 256) {
    unsigned long long p = ((unsigned long long)fmono(skey[k]) << 32) | (unsigned int)k;
    if (p < best[7]) {
      best[7] = p;
#pragma unroll
      for (int t = 7; t > 0; --t)
        if (best[t] < best[t - 1]) {
          unsigned long long tmp = best[t]; best[t] = best[t - 1]; best[t - 1] = tmp;
        }
    }
  }
#pragma unroll
  for (int t = 0; t < 8; ++t) ml[tid][t] = best[t];
  __syncthreads();
  for (int off = 128; off >= 1; off >>= 1) {
    if (tid < off) {
      unsigned long long a[8], b[8], o[8];
#pragma unroll
      for (int t = 0; t < 8; ++t) { a[t] = ml[tid][t]; b[t] = ml[tid + off][t]; }
      int ia = 0, ib = 0;
#pragma unroll
      for (int t = 0; t < 8; ++t) o[t] = (a[ia] <= b[ib]) ? a[ia++] : b[ib++];
#pragma unroll
      for (int t = 0; t < 8; ++t) ml[tid][t] = o[t];
    }
    __syncthreads();
  }
  if (tid == 0) {
    unsigned long long amx = sm4[0];
#pragma unroll
    for (int t = 1; t < 4; ++t) amx = (sm4[t] > amx) ? sm4[t] : amx;
    hardq[crop * BS + j] = (int)(~(unsigned int)(amx & 0xffffffffull));
#pragma unroll
    for (int r = 0; r < 6; ++r)
      negq[(size_t)(crop * BS + j) * 6 + r] = (int)(unsigned int)(ml[0][2 + r] & 0xffffffffull);
  }

  if (crop == 1) {
    const float* xrow = outputAll + (size_t)j * K;
    float mx = -3.4e38f;
    for (int k = tid; k < K; k += 256) mx = fmaxf(mx, xrow[k]);
    mx = wave_max(mx);
    if ((tid & 63) == 0) red[1][tid >> 6] = mx;
    __syncthreads();
    mx = fmaxf(fmaxf(red[1][0], red[1][1]), fmaxf(red[1][2], red[1][3]));
    float se = 0.f, sk = 0.f, skx = 0.f;
    for (int k4 = tid; k4 < K4; k4 += 256) {
      float4 x = reinterpret_cast<const float4*>(xrow)[k4];
      se += expf((x.x - mx) / TEMP) + expf((x.y - mx) / TEMP) +
            expf((x.z - mx) / TEMP) + expf((x.w - mx) / TEMP);
      float4 kv = reinterpret_cast<const float4*>(skey)[k4];
      sk  += kv.x + kv.y + kv.z + kv.w;
      skx += kv.x * x.x + kv.y * x.y + kv.z * x.z + kv.w * x.w;
    }
    se = wave_sum(se); sk = wave_sum(sk); skx = wave_sum(skx);
    if ((tid & 63) == 0) { int w = tid >> 6; red[1][w] = se; red[2][w] = sk; red[3][w] = skx; }
    __syncthreads();
    if (tid == 0) {
      float SE  = red[1][0] + red[1][1] + red[1][2] + red[1][3];
      float SK  = red[2][0] + red[2][1] + red[2][2] + red[2][3];
      float SKX = red[3][0] + red[3][1] + red[3][2] + red[3][3];
      float bv  = 1.0f / sv;
      float sq  = bv * SK;
      float sqx = bv * SKX / TEMP;
      float lse = mx / TEMP + logf(SE);
      atomicAdd(&accum[2], sqx - lse * sq);
    }
  }
}

__global__ __launch_bounds__(256) void k_normalize(
    const float* __restrict__ emb, float* __restrict__ outc) {
  __shared__ float s4[4];
  __shared__ float nrm;
  int r = blockIdx.x;
  int src = (r < BS) ? (BS + r) : (r - BS);
  float z = emb[(size_t)src * DIM + threadIdx.x] / TEMP;
  float ss = wave_sum(z * z);
  if ((threadIdx.x & 63) == 0) s4[threadIdx.x >> 6] = ss;
  __syncthreads();
  if (threadIdx.x == 0) nrm = sqrtf(s4[0] + s4[1] + s4[2] + s4[3]);
  __syncthreads();
  outc[(size_t)r * DIM + threadIdx.x] = z / nrm;
}

__global__ __launch_bounds__(256) void k_pos(
    const float* __restrict__ outc, float* __restrict__ accum) {
  int wid = threadIdx.x >> 6, lane = threadIdx.x & 63;
  int j = blockIdx.x * 4 + wid;
  const float4 a = reinterpret_cast<const float4*>(outc + (size_t)j * DIM)[lane];
  const float4 b = reinterpret_cast<const float4*>(outc + (size_t)(BS + j) * DIM)[lane];
  float d = a.x * b.x + a.y * b.y + a.z * b.z + a.w * b.w;
  d = wave_sum(d);
  if (lane == 0) atomicAdd(&accum[1], d);
}

// -------- denom: compact member list, then full-wave dots --------
__global__ __launch_bounds__(256) void k_denom(
    const float* __restrict__ outc, const int* __restrict__ hardq,
    const int* __restrict__ negq, float* __restrict__ accum) {
  __shared__ int shq[N2];
  __shared__ float4 srow[64];
  __shared__ int list[N2];
  __shared__ int cnt;
  __shared__ float s4[4];
  const int i = blockIdx.x;
  const int tid = threadIdx.x;
  const int wid = tid >> 6, lane = tid & 63;
  if (tid == 0) cnt = 0;
  for (int t = tid; t < N2; t += 256) shq[t] = hardq[t];
  if (tid < 64) srow[tid] = reinterpret_cast<const float4*>(outc + (size_t)i * DIM)[tid];
  int q0 = negq[i * 6 + 0], q1 = negq[i * 6 + 1], q2 = negq[i * 6 + 2],
      q3 = negq[i * 6 + 3], q4 = negq[i * 6 + 4], q5 = negq[i * 6 + 5];
  __syncthreads();
  for (int jj = tid; jj < N2; jj += 256) {
    if (jj == i) continue;
    int h = shq[jj];
    if (h == q0 || h == q1 || h == q2 || h == q3 || h == q4 || h == q5) {
      int p = atomicAdd(&cnt, 1);
      list[p] = jj;
    }
  }
  __syncthreads();
  const int n = cnt;
  float acc = 0.f;
  for (int m = wid; m < n; m += 4) {
    int jj = list[m];
    float4 a = srow[lane];
    float4 b = reinterpret_cast<const float4*>(outc + (size_t)jj * DIM)[lane];
    float d = a.x * b.x + a.y * b.y + a.z * b.z + a.w * b.w;
    d = wave_sum(d);
    if (lane == 0) acc += expf(d / TEMP);
  }
  if (lane == 0) s4[wid] = acc;
  __syncthreads();
  if (tid == 0) atomicAdd(&accum[0], s4[0] + s4[1] + s4[2] + s4[3]);
}

__global__ void k_final(const float* __restrict__ accum, float* __restrict__ out) {
  float denom  = accum[0];
  float possum = accum[1];
  float ccsum  = accum[2];
  float contrast = logf(denom) - possum / ((float)BS * TEMP);
  float cc_loss  = -ccsum / (float)BS;
  out[0] = contrast + 6.0f * cc_loss;
}

}  // namespace

extern "C" void kernel_launch(void* const* d_in, const int* in_sizes, int n_in,
                              void* d_out, int out_size, void* d_ws, size_t ws_size,
                              hipStream_t stream) {
  const float* queue  = (const float*)d_in[3];  // [2][QL][DIM]
  const float* proto  = (const float*)d_in[4];  // [K][DIM]
  const float* output = (const float*)d_in[5];  // [2*BS][K]
  const float* emb    = (const float*)d_in[6];  // [2*BS][DIM]
  float* ws = (float*)d_ws;
  ushort* M   = (ushort*)(ws + OFF_M);
  float* S    = ws + OFF_S;                     // S1,S2,S3 each KP
  float* accum = ws + OFF_ACC;
  int* hardq = (int*)(ws + OFF_HQ);
  int* negq  = (int*)(ws + OFF_NQ);
  ushort* cvt_hi = (ushort*)(ws + OFF_CVT_HI);
  ushort* cvt_lo = (ushort*)(ws + OFF_CVT_LO);
  float* outc  = ws + OFF_OUTC;
  float* out = (float*)d_out;

  hipMemsetAsync(accum, 0, 8 * sizeof(float), stream);

  {
    int n4q = 2 * QL * DIM / 4;
    k_convert<<<(n4q + 255) / 256, 256, 0, stream>>>(queue, cvt_hi, cvt_lo, n4q);
    int n4p = K * DIM / 4;
    k_convert<<<(n4p + 255) / 256, 256, 0, stream>>>(
        proto, cvt_hi + (size_t)2 * QL * DIM, cvt_lo + (size_t)2 * QL * DIM, n4p);
  }

  for (int crop = 0; crop < 2; ++crop) {
    const float* ocrop = output + (size_t)crop * BS * K;
    const ushort* Ahi = cvt_hi + (size_t)crop * QL * DIM;
    const ushort* Alo = cvt_lo + (size_t)crop * QL * DIM;
    const ushort* Bhi = cvt_hi + (size_t)2 * QL * DIM;
    const ushort* Blo = cvt_lo + (size_t)2 * QL * DIM;
    float* S1 = S;
    float* S2 = S + KP;
    float* S3 = S + 2 * KP;

    hipMemsetAsync(S, 0, 3 * KP * sizeof(float), stream);
    k_gemm_split<<<dim3((K + 127) / 128, QL / 128), 256, 0, stream>>>(
        Ahi, Alo, Bhi, Blo, M, S1);
    k_initsample<<<dim3((KP4 + 255) / 256, BS / 32), 256, 0, stream>>>(ocrop, M, S1);
    k_sink_fused<<<NTOT / ROWS_PER_BLK, 256, 0, stream>>>(M, S1, S2);
    k_sink_fused<<<NTOT / ROWS_PER_BLK, 256, 0, stream>>>(M, S2, S3);
    k_stats<<<BS, 256, 0, stream>>>(output, S3, crop, hardq, negq, accum);
  }

  k_normalize<<<N2, 256, 0, stream>>>(emb, outc);
  k_pos<<<BS / 4, 256, 0, stream>>>(outc, accum);
  k_denom<<<N2, 256, 0, stream>>>(outc, hardq, negq, accum);
  k_final<<<1, 1, 0, stream>>>(accum, out);
}

// Round 4
// 414.117 us; speedup vs baseline: 1.8348x; 1.8348x over previous
//
#include <hip/hip_runtime.h>
#include <hip/hip_bf16.h>
#include <cstdint>

namespace {

constexpr int BS   = 2048;
constexpr int DIM  = 256;
constexpr int K    = 3000;
constexpr int K4   = K / 4;        // 750
constexpr int KP   = 3008;         // padded row stride (bf16 matrix)
constexpr int KP4  = KP / 4;       // 752
constexpr int QL   = 3840;
constexpr int NTOT = QL + BS;      // 5888
constexpr int N2   = 2 * BS;       // 4096
constexpr int NDBLK = N2 * 6 / 4;  // 6144 denom blocks (4 waves each)
constexpr float TEMP = 0.2f;
constexpr float INV_EPS = 20.0f;
constexpr float KF = 3000.0f;

// ws layout (float indices)
constexpr size_t OFF_M    = 0;                           // NTOT*KP/2
constexpr size_t OFF_S    = OFF_M + (size_t)NTOT * KP / 2;  // 3*KP
constexpr size_t OFF_ACC  = OFF_S + 3 * KP;              // 8
constexpr size_t OFF_V    = OFF_ACC + 8;                 // NTOT
constexpr size_t OFF_HQ   = OFF_V + NTOT;                // N2 ints
constexpr size_t OFF_NQ   = OFF_HQ + N2;                 // N2*6 ints
constexpr size_t OFF_CNT  = OFF_NQ + (size_t)N2 * 6;     // 3008 ints
constexpr size_t OFF_OFFA = OFF_CNT + 3008;              // 3072 ints
constexpr size_t OFF_CUR  = OFF_OFFA + 3072;             // 3008 ints
constexpr size_t OFF_BUCKET = OFF_CUR + 3008;            // N2 ints
constexpr size_t OFF_PART = OFF_BUCKET + N2;             // NDBLK floats
constexpr size_t OFF_CVT  = ((OFF_PART + NDBLK + 15) / 16) * 16;
constexpr size_t CVT_ELEM = (size_t)(2 * QL + K) * DIM;  // ushorts
constexpr size_t CVT_FL   = CVT_ELEM / 2;
constexpr size_t OFF_CVT_HI = OFF_CVT;
constexpr size_t OFF_CVT_LO = OFF_CVT_HI + CVT_FL;
constexpr size_t OFF_OUTC   = OFF_CVT_HI;                // reuse after GEMMs

using bf16x8 = __attribute__((ext_vector_type(8))) short;
using f32x4  = __attribute__((ext_vector_type(4))) float;

__device__ __forceinline__ float wave_sum(float v) {
#pragma unroll
  for (int off = 32; off > 0; off >>= 1) v += __shfl_down(v, off, 64);
  return v;
}
__device__ __forceinline__ float wave_max(float v) {
#pragma unroll
  for (int off = 32; off > 0; off >>= 1) v = fmaxf(v, __shfl_down(v, off, 64));
  return v;
}
__device__ __forceinline__ unsigned long long wave_maxu64(unsigned long long v) {
#pragma unroll
  for (int off = 32; off > 0; off >>= 1) {
    unsigned long long o = __shfl_down(v, off, 64);
    v = (o > v) ? o : v;
  }
  return v;
}
__device__ __forceinline__ unsigned int fmono(float f) {
  unsigned int u = __float_as_uint(f);
  return (u & 0x80000000u) ? ~u : (u | 0x80000000u);
}
__device__ __forceinline__ float bf2f(short s) {
  return __uint_as_float(((unsigned int)(unsigned short)s) << 16);
}
__device__ __forceinline__ ushort f2bf(float f) {
  __hip_bfloat16 b = __float2bfloat16(f);
  return *reinterpret_cast<ushort*>(&b);
}

// -------- split f32 -> (hi, lo) bf16 --------
__global__ __launch_bounds__(256) void k_convert(
    const float* __restrict__ x, ushort* __restrict__ hi, ushort* __restrict__ lo, int n4) {
  int i = blockIdx.x * 256 + threadIdx.x;
  if (i >= n4) return;
  float4 v = reinterpret_cast<const float4*>(x)[i];
  ushort4 h, l;
  h.x = f2bf(v.x); l.x = f2bf(v.x - bf2f((short)h.x));
  h.y = f2bf(v.y); l.y = f2bf(v.y - bf2f((short)h.y));
  h.z = f2bf(v.z); l.z = f2bf(v.z - bf2f((short)h.z));
  h.w = f2bf(v.w); l.w = f2bf(v.w - bf2f((short)h.w));
  reinterpret_cast<ushort4*>(hi)[i] = h;
  reinterpret_cast<ushort4*>(lo)[i] = l;
}

// -------- MFMA GEMM: M[m][n] = bf16(exp(dot/EPS)) (queue rows); S += colsum --------
__global__ __launch_bounds__(256) void k_gemm_split(
    const ushort* __restrict__ Ahi_g, const ushort* __restrict__ Alo_g,
    const ushort* __restrict__ Bhi_g, const ushort* __restrict__ Blo_g,
    ushort* __restrict__ M, float* __restrict__ S) {
  __shared__ ushort Ah[128][40], Al[128][40], Bh[128][40], Bl[128][40];
  const int tid  = threadIdx.x;
  const int bn0  = blockIdx.x * 128;
  const int bm0  = blockIdx.y * 128;
  const int wid  = tid >> 6, lane = tid & 63;
  const int wm0  = (wid >> 1) * 64, wn0 = (wid & 1) * 64;
  const int ln15 = lane & 15, lq = lane >> 4;
  const int lr   = tid >> 2;
  const int lc   = (tid & 3) * 8;

  f32x4 acc[4][4] = {};

  for (int kk = 0; kk < DIM; kk += 32) {
#pragma unroll
    for (int p = 0; p < 2; ++p) {
      int row = p * 64 + lr;
      size_t ga = (size_t)(bm0 + row) * DIM + kk + lc;
      int brow = bn0 + row; if (brow >= K) brow = K - 1;
      size_t gb = (size_t)brow * DIM + kk + lc;
      *reinterpret_cast<bf16x8*>(&Ah[row][lc]) = *reinterpret_cast<const bf16x8*>(&Ahi_g[ga]);
      *reinterpret_cast<bf16x8*>(&Al[row][lc]) = *reinterpret_cast<const bf16x8*>(&Alo_g[ga]);
      *reinterpret_cast<bf16x8*>(&Bh[row][lc]) = *reinterpret_cast<const bf16x8*>(&Bhi_g[gb]);
      *reinterpret_cast<bf16x8*>(&Bl[row][lc]) = *reinterpret_cast<const bf16x8*>(&Blo_g[gb]);
    }
    __syncthreads();
    bf16x8 ah[4], al[4], bh[4], bl[4];
#pragma unroll
    for (int i = 0; i < 4; ++i) {
      ah[i] = *reinterpret_cast<const bf16x8*>(&Ah[wm0 + i * 16 + ln15][lq * 8]);
      al[i] = *reinterpret_cast<const bf16x8*>(&Al[wm0 + i * 16 + ln15][lq * 8]);
      bh[i] = *reinterpret_cast<const bf16x8*>(&Bh[wn0 + i * 16 + ln15][lq * 8]);
      bl[i] = *reinterpret_cast<const bf16x8*>(&Bl[wn0 + i * 16 + ln15][lq * 8]);
    }
#pragma unroll
    for (int i = 0; i < 4; ++i)
#pragma unroll
      for (int j = 0; j < 4; ++j) {
        acc[i][j] = __builtin_amdgcn_mfma_f32_16x16x32_bf16(ah[i], bh[j], acc[i][j], 0, 0, 0);
        acc[i][j] = __builtin_amdgcn_mfma_f32_16x16x32_bf16(ah[i], bl[j], acc[i][j], 0, 0, 0);
        acc[i][j] = __builtin_amdgcn_mfma_f32_16x16x32_bf16(al[i], bh[j], acc[i][j], 0, 0, 0);
      }
    __syncthreads();
  }

#pragma unroll
  for (int j = 0; j < 4; ++j) {
    int col = bn0 + wn0 + j * 16 + ln15;
    bool valid = col < K;
    bool inmat = col < KP;
    float csum = 0.f;
#pragma unroll
    for (int i = 0; i < 4; ++i) {
      int rowb = bm0 + wm0 + i * 16 + lq * 4;
#pragma unroll
      for (int r = 0; r < 4; ++r) {
        float q = valid ? expf(acc[i][j][r] * INV_EPS) : 0.f;
        if (inmat) M[(size_t)(rowb + r) * KP + col] = f2bf(q);
        csum += q;
      }
    }
    csum += __shfl_xor(csum, 16, 64);
    csum += __shfl_xor(csum, 32, 64);
    if (lane < 16 && valid) atomicAdd(&S[col], csum);
  }
}

// -------- sample rows: exp -> bf16 matrix rows + v0-colsum into S --------
__global__ __launch_bounds__(256) void k_initsample(
    const float* __restrict__ outCrop, ushort* __restrict__ M, float* __restrict__ S) {
  int k4 = blockIdx.x * 256 + threadIdx.x;
  if (k4 >= KP4) return;
  bool pad = k4 >= K4;
  int r0 = blockIdx.y * 16;
  float ax = 0.f, ay = 0.f, az = 0.f, aw = 0.f;
  for (int rr = 0; rr < 16; ++rr) {
    int row = r0 + rr;
    ushort4 w = make_ushort4(0, 0, 0, 0);
    if (!pad) {
      float4 x = reinterpret_cast<const float4*>(outCrop + (size_t)row * K)[k4];
      float ex = expf(x.x * INV_EPS), ey = expf(x.y * INV_EPS),
            ez = expf(x.z * INV_EPS), ew = expf(x.w * INV_EPS);
      ax += ex; ay += ey; az += ez; aw += ew;
      w.x = f2bf(ex); w.y = f2bf(ey); w.z = f2bf(ez); w.w = f2bf(ew);
    }
    reinterpret_cast<ushort4*>(M + (size_t)(QL + row) * KP)[k4] = w;
  }
  if (!pad) {
    atomicAdd(&S[k4 * 4 + 0], ax);
    atomicAdd(&S[k4 * 4 + 1], ay);
    atomicAdd(&S[k4 * 4 + 2], az);
    atomicAdd(&S[k4 * 4 + 3], aw);
  }
}

// -------- rowpass: v[n] = 1/(NTOT * sum_k M[n][k]/(K*S_in[k])) --------
__global__ __launch_bounds__(256) void k_rowpass(
    const ushort* __restrict__ M, const float* __restrict__ S_in, float* __restrict__ v) {
  __shared__ float red[4];
  const int tid = threadIdx.x;
  const int n = blockIdx.x;
  const ushort* row = M + (size_t)n * KP;
  const int g1 = tid, g2 = tid + 256;
  const bool has2 = g2 < KP / 8;            // 376 groups of 8
  const bool pad2 = has2 && (g2 == 375);    // cols 3000..3007

  float ua[8], ub[8];
  {
    float4 s0 = reinterpret_cast<const float4*>(S_in)[g1 * 2];
    float4 s1 = reinterpret_cast<const float4*>(S_in)[g1 * 2 + 1];
    ua[0] = 1.0f / (KF * s0.x); ua[1] = 1.0f / (KF * s0.y);
    ua[2] = 1.0f / (KF * s0.z); ua[3] = 1.0f / (KF * s0.w);
    ua[4] = 1.0f / (KF * s1.x); ua[5] = 1.0f / (KF * s1.y);
    ua[6] = 1.0f / (KF * s1.z); ua[7] = 1.0f / (KF * s1.w);
  }
  if (has2 && !pad2) {
    float4 s0 = reinterpret_cast<const float4*>(S_in)[g2 * 2];
    float4 s1 = reinterpret_cast<const float4*>(S_in)[g2 * 2 + 1];
    ub[0] = 1.0f / (KF * s0.x); ub[1] = 1.0f / (KF * s0.y);
    ub[2] = 1.0f / (KF * s0.z); ub[3] = 1.0f / (KF * s0.w);
    ub[4] = 1.0f / (KF * s1.x); ub[5] = 1.0f / (KF * s1.y);
    ub[6] = 1.0f / (KF * s1.z); ub[7] = 1.0f / (KF * s1.w);
  } else {
#pragma unroll
    for (int e = 0; e < 8; ++e) ub[e] = 0.f;
  }

  float s = 0.f;
  {
    bf16x8 a = *reinterpret_cast<const bf16x8*>(&row[g1 * 8]);
#pragma unroll
    for (int e = 0; e < 8; ++e) s += bf2f(a[e]) * ua[e];
    if (has2) {
      bf16x8 c = *reinterpret_cast<const bf16x8*>(&row[g2 * 8]);
#pragma unroll
      for (int e = 0; e < 8; ++e) s += bf2f(c[e]) * ub[e];
    }
  }
  s = wave_sum(s);
  if ((tid & 63) == 0) red[tid >> 6] = s;
  __syncthreads();
  if (tid == 0) v[n] = 1.0f / ((float)NTOT * (red[0] + red[1] + red[2] + red[3]));
}

// -------- colsum: S_out[k] = sum_n M[n][k]*v[n] --------
__global__ __launch_bounds__(256) void k_colsum(
    const ushort* __restrict__ M, const float* __restrict__ v, float* __restrict__ S_out) {
  __shared__ float vsh[32];
  const int tid = threadIdx.x;
  const int g = blockIdx.x * 256 + tid;     // ushort4 group, 752 total
  const int n0 = blockIdx.y * 32;
  if (tid < 32) vsh[tid] = v[n0 + tid];
  __syncthreads();
  if (g >= KP4) return;
  float c0 = 0.f, c1 = 0.f, c2 = 0.f, c3 = 0.f;
#pragma unroll 8
  for (int rr = 0; rr < 32; ++rr) {
    ushort4 m = reinterpret_cast<const ushort4*>(M + (size_t)(n0 + rr) * KP)[g];
    float vr = vsh[rr];
    c0 += bf2f((short)m.x) * vr;
    c1 += bf2f((short)m.y) * vr;
    c2 += bf2f((short)m.z) * vr;
    c3 += bf2f((short)m.w) * vr;
  }
  atomicAdd(&S_out[g * 4 + 0], c0);
  atomicAdd(&S_out[g * 4 + 1], c1);
  atomicAdd(&S_out[g * 4 + 2], c2);
  atomicAdd(&S_out[g * 4 + 3], c3);
}

// -------- per sample row: hard_q, neg_q, fused final-v, crop-1 cc term --------
__global__ __launch_bounds__(256) void k_stats(
    const float* __restrict__ outputAll, const float* __restrict__ S3,
    int crop, int* __restrict__ hardq, int* __restrict__ negq, float* __restrict__ accum) {
  __shared__ float skey[K];
  __shared__ unsigned long long ml[256][8];
  __shared__ unsigned long long sm4[4];
  __shared__ float red[4][4];
  const int tid = threadIdx.x;
  const int j = blockIdx.x;
  const float* orow = outputAll + (size_t)(crop * BS + j) * K;

  float svp = 0.f;
  for (int k4 = tid; k4 < K4; k4 += 256) {
    float4 o = reinterpret_cast<const float4*>(orow)[k4];
    float4 s = reinterpret_cast<const float4*>(S3)[k4];
    float4 kv;
    kv.x = expf(o.x * INV_EPS) / (KF * s.x);
    kv.y = expf(o.y * INV_EPS) / (KF * s.y);
    kv.z = expf(o.z * INV_EPS) / (KF * s.z);
    kv.w = expf(o.w * INV_EPS) / (KF * s.w);
    reinterpret_cast<float4*>(skey)[k4] = kv;
    svp += kv.x + kv.y + kv.z + kv.w;
  }
  svp = wave_sum(svp);
  if ((tid & 63) == 0) red[0][tid >> 6] = svp;
  __syncthreads();
  const float sv = red[0][0] + red[0][1] + red[0][2] + red[0][3];

  unsigned long long am = 0ull;
  for (int k = tid; k < K; k += 256) {
    unsigned long long p = ((unsigned long long)fmono(skey[k]) << 32) | (unsigned int)(~k);
    am = (p > am) ? p : am;
  }
  am = wave_maxu64(am);
  if ((tid & 63) == 0) sm4[tid >> 6] = am;

  unsigned long long best[8];
#pragma unroll
  for (int t = 0; t < 8; ++t) best[t] = ~0ull;
  for (int k = tid; k < K; k += 256) {
    unsigned long long p = ((unsigned long long)fmono(skey[k]) << 32) | (unsigned int)k;
    if (p < best[7]) {
      best[7] = p;
#pragma unroll
      for (int t = 7; t > 0; --t)
        if (best[t] < best[t - 1]) {
          unsigned long long tmp = best[t]; best[t] = best[t - 1]; best[t - 1] = tmp;
        }
    }
  }
#pragma unroll
  for (int t = 0; t < 8; ++t) ml[tid][t] = best[t];
  __syncthreads();
  for (int off = 128; off >= 1; off >>= 1) {
    if (tid < off) {
      unsigned long long a[8], b[8], o[8];
#pragma unroll
      for (int t = 0; t < 8; ++t) { a[t] = ml[tid][t]; b[t] = ml[tid + off][t]; }
      int ia = 0, ib = 0;
#pragma unroll
      for (int t = 0; t < 8; ++t) o[t] = (a[ia] <= b[ib]) ? a[ia++] : b[ib++];
#pragma unroll
      for (int t = 0; t < 8; ++t) ml[tid][t] = o[t];
    }
    __syncthreads();
  }
  if (tid == 0) {
    unsigned long long amx = sm4[0];
#pragma unroll
    for (int t = 1; t < 4; ++t) amx = (sm4[t] > amx) ? sm4[t] : amx;
    hardq[crop * BS + j] = (int)(~(unsigned int)(amx & 0xffffffffull));
#pragma unroll
    for (int r = 0; r < 6; ++r)
      negq[(size_t)(crop * BS + j) * 6 + r] = (int)(unsigned int)(ml[0][2 + r] & 0xffffffffull);
  }

  if (crop == 1) {
    const float* xrow = outputAll + (size_t)j * K;
    float mx = -3.4e38f;
    for (int k = tid; k < K; k += 256) mx = fmaxf(mx, xrow[k]);
    mx = wave_max(mx);
    if ((tid & 63) == 0) red[1][tid >> 6] = mx;
    __syncthreads();
    mx = fmaxf(fmaxf(red[1][0], red[1][1]), fmaxf(red[1][2], red[1][3]));
    float se = 0.f, sk = 0.f, skx = 0.f;
    for (int k4 = tid; k4 < K4; k4 += 256) {
      float4 x = reinterpret_cast<const float4*>(xrow)[k4];
      se += expf((x.x - mx) / TEMP) + expf((x.y - mx) / TEMP) +
            expf((x.z - mx) / TEMP) + expf((x.w - mx) / TEMP);
      float4 kv = reinterpret_cast<const float4*>(skey)[k4];
      sk  += kv.x + kv.y + kv.z + kv.w;
      skx += kv.x * x.x + kv.y * x.y + kv.z * x.z + kv.w * x.w;
    }
    se = wave_sum(se); sk = wave_sum(sk); skx = wave_sum(skx);
    if ((tid & 63) == 0) { int w = tid >> 6; red[1][w] = se; red[2][w] = sk; red[3][w] = skx; }
    __syncthreads();
    if (tid == 0) {
      float SE  = red[1][0] + red[1][1] + red[1][2] + red[1][3];
      float SK  = red[2][0] + red[2][1] + red[2][2] + red[2][3];
      float SKX = red[3][0] + red[3][1] + red[3][2] + red[3][3];
      float bv  = 1.0f / sv;
      float sq  = bv * SK;
      float sqx = bv * SKX / TEMP;
      float lse = mx / TEMP + logf(SE);
      atomicAdd(&accum[2], sqx - lse * sq);
    }
  }
}

__global__ __launch_bounds__(256) void k_normalize(
    const float* __restrict__ emb, float* __restrict__ outc) {
  __shared__ float s4[4];
  __shared__ float nrm;
  int r = blockIdx.x;
  int src = (r < BS) ? (BS + r) : (r - BS);
  float z = emb[(size_t)src * DIM + threadIdx.x] / TEMP;
  float ss = wave_sum(z * z);
  if ((threadIdx.x & 63) == 0) s4[threadIdx.x >> 6] = ss;
  __syncthreads();
  if (threadIdx.x == 0) nrm = sqrtf(s4[0] + s4[1] + s4[2] + s4[3]);
  __syncthreads();
  outc[(size_t)r * DIM + threadIdx.x] = z / nrm;
}

__global__ __launch_bounds__(256) void k_pos(
    const float* __restrict__ outc, float* __restrict__ accum) {
  int wid = threadIdx.x >> 6, lane = threadIdx.x & 63;
  int j = blockIdx.x * 4 + wid;
  const float4 a = reinterpret_cast<const float4*>(outc + (size_t)j * DIM)[lane];
  const float4 b = reinterpret_cast<const float4*>(outc + (size_t)(BS + j) * DIM)[lane];
  float d = a.x * b.x + a.y * b.y + a.z * b.z + a.w * b.w;
  d = wave_sum(d);
  if (lane == 0) atomicAdd(&accum[1], d);
}

// -------- denom via class histogram --------
__global__ __launch_bounds__(256) void k_hist(
    const int* __restrict__ hardq, int* __restrict__ cnt) {
  int j = blockIdx.x * 256 + threadIdx.x;
  atomicAdd(&cnt[hardq[j]], 1);
}

__global__ __launch_bounds__(256) void k_scan(
    const int* __restrict__ cnt, int* __restrict__ offa) {
  __shared__ int wsum[4];
  __shared__ int wpre[4];
  const int tid = threadIdx.x;
  const int lane = tid & 63, wid = tid >> 6;
  const int base = tid * 12;
  int loc[12];
  int s = 0;
#pragma unroll
  for (int t = 0; t < 12; ++t) {
    int idx = base + t;
    int cv = (idx < K) ? cnt[idx] : 0;
    loc[t] = cv; s += cv;
  }
  int vincl = s;
#pragma unroll
  for (int d = 1; d < 64; d <<= 1) {
    int t = __shfl_up(vincl, d, 64);
    if (lane >= d) vincl += t;
  }
  if (lane == 63) wsum[wid] = vincl;
  __syncthreads();
  if (tid == 0) {
    int r = 0;
#pragma unroll
    for (int w = 0; w < 4; ++w) { wpre[w] = r; r += wsum[w]; }
  }
  __syncthreads();
  int run = vincl - s + wpre[wid];
#pragma unroll
  for (int t = 0; t < 12; ++t) {
    int idx = base + t;
    if (idx < K) { offa[idx] = run; run += loc[t]; }
  }
  if (tid == 255) offa[K] = run;
}

__global__ __launch_bounds__(256) void k_scatter(
    const int* __restrict__ hardq, const int* __restrict__ offa,
    int* __restrict__ cur, int* __restrict__ bucket) {
  int j = blockIdx.x * 256 + threadIdx.x;
  int c = hardq[j];
  int p = atomicAdd(&cur[c], 1);
  bucket[offa[c] + p] = j;
}

// wave per (i, slot): dots against all j with hardq[j]==negq[i][slot]
__global__ __launch_bounds__(256) void k_denom2(
    const float* __restrict__ outc, const int* __restrict__ negq,
    const int* __restrict__ offa, const int* __restrict__ bucket,
    float* __restrict__ partial) {
  __shared__ float s4[4];
  const int tid = threadIdx.x;
  const int wid = tid >> 6, lane = tid & 63;
  const int task = blockIdx.x * 4 + wid;
  const int i = task / 6, slot = task - i * 6;
  const int c = negq[i * 6 + slot];
  const int lo = offa[c];
  const int n = offa[c + 1] - lo;
  float acc = 0.f;
  if (n > 0) {
    const float4 a = reinterpret_cast<const float4*>(outc + (size_t)i * DIM)[lane];
    for (int m = 0; m < n; ++m) {
      int j = bucket[lo + m];
      if (j == i) continue;
      const float4 b = reinterpret_cast<const float4*>(outc + (size_t)j * DIM)[lane];
      float d = a.x * b.x + a.y * b.y + a.z * b.z + a.w * b.w;
      d = wave_sum(d);
      if (lane == 0) acc += expf(d * 5.0f);
    }
  }
  if (lane == 0) s4[wid] = acc;
  __syncthreads();
  if (tid == 0) partial[blockIdx.x] = s4[0] + s4[1] + s4[2] + s4[3];
}

__global__ __launch_bounds__(256) void k_final(
    const float* __restrict__ accum, const float* __restrict__ partial,
    float* __restrict__ out) {
  __shared__ float s4[4];
  const int tid = threadIdx.x;
  float s = 0.f;
  for (int m = tid; m < NDBLK; m += 256) s += partial[m];
  s = wave_sum(s);
  if ((tid & 63) == 0) s4[tid >> 6] = s;
  __syncthreads();
  if (tid == 0) {
    float denom = s4[0] + s4[1] + s4[2] + s4[3];
    float possum = accum[1];
    float ccsum  = accum[2];
    float contrast = logf(denom) - possum / ((float)BS * TEMP);
    out[0] = contrast - 6.0f * ccsum / (float)BS;
  }
}

}  // namespace

extern "C" void kernel_launch(void* const* d_in, const int* in_sizes, int n_in,
                              void* d_out, int out_size, void* d_ws, size_t ws_size,
                              hipStream_t stream) {
  const float* queue  = (const float*)d_in[3];  // [2][QL][DIM]
  const float* proto  = (const float*)d_in[4];  // [K][DIM]
  const float* output = (const float*)d_in[5];  // [2*BS][K]
  const float* emb    = (const float*)d_in[6];  // [2*BS][DIM]
  float* ws = (float*)d_ws;
  ushort* M    = (ushort*)(ws + OFF_M);
  float* S     = ws + OFF_S;
  float* accum = ws + OFF_ACC;
  float* v     = ws + OFF_V;
  int* hardq   = (int*)(ws + OFF_HQ);
  int* negq    = (int*)(ws + OFF_NQ);
  int* cnt     = (int*)(ws + OFF_CNT);
  int* offa    = (int*)(ws + OFF_OFFA);
  int* cur     = (int*)(ws + OFF_CUR);
  int* bucket  = (int*)(ws + OFF_BUCKET);
  float* partial = ws + OFF_PART;
  ushort* cvt_hi = (ushort*)(ws + OFF_CVT_HI);
  ushort* cvt_lo = (ushort*)(ws + OFF_CVT_LO);
  float* outc  = ws + OFF_OUTC;
  float* out = (float*)d_out;

  hipMemsetAsync(accum, 0, 8 * sizeof(float), stream);
  // zero cnt + offa + cur (contiguous)
  hipMemsetAsync(cnt, 0, (3008 + 3072 + 3008) * sizeof(int), stream);

  {
    int n4q = 2 * QL * DIM / 4;
    k_convert<<<(n4q + 255) / 256, 256, 0, stream>>>(queue, cvt_hi, cvt_lo, n4q);
    int n4p = K * DIM / 4;
    k_convert<<<(n4p + 255) / 256, 256, 0, stream>>>(
        proto, cvt_hi + (size_t)2 * QL * DIM, cvt_lo + (size_t)2 * QL * DIM, n4p);
  }

  for (int crop = 0; crop < 2; ++crop) {
    const float* ocrop = output + (size_t)crop * BS * K;
    const ushort* Ahi = cvt_hi + (size_t)crop * QL * DIM;
    const ushort* Alo = cvt_lo + (size_t)crop * QL * DIM;
    const ushort* Bhi = cvt_hi + (size_t)2 * QL * DIM;
    const ushort* Blo = cvt_lo + (size_t)2 * QL * DIM;
    float* S1 = S;
    float* S2 = S + KP;
    float* S3 = S + 2 * KP;

    hipMemsetAsync(S, 0, 3 * KP * sizeof(float), stream);
    k_gemm_split<<<dim3((K + 127) / 128, QL / 128), 256, 0, stream>>>(
        Ahi, Alo, Bhi, Blo, M, S1);
    k_initsample<<<dim3((KP4 + 255) / 256, BS / 16), 256, 0, stream>>>(ocrop, M, S1);
    k_rowpass<<<NTOT, 256, 0, stream>>>(M, S1, v);
    k_colsum<<<dim3(3, NTOT / 32), 256, 0, stream>>>(M, v, S2);
    k_rowpass<<<NTOT, 256, 0, stream>>>(M, S2, v);
    k_colsum<<<dim3(3, NTOT / 32), 256, 0, stream>>>(M, v, S3);
    k_stats<<<BS, 256, 0, stream>>>(output, S3, crop, hardq, negq, accum);
  }

  k_normalize<<<N2, 256, 0, stream>>>(emb, outc);
  k_pos<<<BS / 4, 256, 0, stream>>>(outc, accum);
  k_hist<<<N2 / 256, 256, 0, stream>>>(hardq, cnt);
  k_scan<<<1, 256, 0, stream>>>(cnt, offa);
  k_scatter<<<N2 / 256, 256, 0, stream>>>(hardq, offa, cur, bucket);
  k_denom2<<<NDBLK, 256, 0, stream>>>(outc, negq, offa, bucket, partial);
  k_final<<<1, 256, 0, stream>>>(accum, partial, out);
}

// Round 5
// 354.651 us; speedup vs baseline: 2.1424x; 1.1677x over previous
//
#include <hip/hip_runtime.h>
#include <hip/hip_bf16.h>
#include <cstdint>

namespace {

constexpr int BS   = 2048;
constexpr int DIM  = 256;
constexpr int K    = 3000;
constexpr int K4   = K / 4;        // 750
constexpr int KP   = 3008;         // padded row stride (bf16 matrix)
constexpr int KP4  = KP / 4;       // 752
constexpr int QL   = 3840;
constexpr int NTOT = QL + BS;      // 5888
constexpr int N2   = 2 * BS;       // 4096
constexpr int NDBLK = N2 * 6 / 4;  // 6144
constexpr float TEMP = 0.2f;
constexpr float INV_EPS = 20.0f;
constexpr float KF = 3000.0f;

// ws layout (float indices)
constexpr size_t OFF_M    = 0;                              // NTOT*KP/2
constexpr size_t OFF_S    = OFF_M + (size_t)NTOT * KP / 2;  // 6*KP (S1..S3 x2 crops)
constexpr size_t OFF_ACC  = OFF_S + 6 * KP;                 // 8
constexpr size_t OFF_CNT  = OFF_ACC + 8;                    // 3008 ints
constexpr size_t OFF_OFFA = OFF_CNT + 3008;                 // 3072 ints
constexpr size_t OFF_CUR  = OFF_OFFA + 3072;                // 3008 ints
constexpr size_t OFF_V    = OFF_CUR + 3008;                 // NTOT
constexpr size_t OFF_HQ   = OFF_V + NTOT;                   // N2 ints
constexpr size_t OFF_NQ   = OFF_HQ + N2;                    // N2*6 ints
constexpr size_t OFF_LOGU = OFF_NQ + (size_t)N2 * 6;        // 3008
constexpr size_t OFF_BUCKET = OFF_LOGU + 3008;              // N2 ints
constexpr size_t OFF_PART = OFF_BUCKET + N2;                // NDBLK
constexpr size_t OFF_CVT  = ((OFF_PART + NDBLK + 15) / 16) * 16;
constexpr size_t OFF_OUTC = OFF_CVT;                        // reuse after GEMMs

using bf16x8 = __attribute__((ext_vector_type(8))) short;
using f32x4  = __attribute__((ext_vector_type(4))) float;
typedef unsigned long long ull;

__device__ __forceinline__ float wave_sum(float v) {
#pragma unroll
  for (int off = 32; off > 0; off >>= 1) v += __shfl_down(v, off, 64);
  return v;
}
__device__ __forceinline__ float wave_max(float v) {
#pragma unroll
  for (int off = 32; off > 0; off >>= 1) v = fmaxf(v, __shfl_down(v, off, 64));
  return v;
}
__device__ __forceinline__ ull wave_maxu64(ull v) {
#pragma unroll
  for (int off = 32; off > 0; off >>= 1) {
    ull o = __shfl_down(v, off, 64);
    v = (o > v) ? o : v;
  }
  return v;
}
__device__ __forceinline__ unsigned int fmono(float f) {
  unsigned int u = __float_as_uint(f);
  return (u & 0x80000000u) ? ~u : (u | 0x80000000u);
}
__device__ __forceinline__ float bf2f(short s) {
  return __uint_as_float(((unsigned int)(unsigned short)s) << 16);
}
__device__ __forceinline__ ushort f2bf(float f) {
  __hip_bfloat16 b = __float2bfloat16(f);
  return *reinterpret_cast<ushort*>(&b);
}

#define CEX(m, i, j) { ull aa = m[i], bb = m[j]; m[i] = aa < bb ? aa : bb; m[j] = aa < bb ? bb : aa; }

// merge two ascending 8-lists -> ascending bottom-8 of union (static indices)
__device__ __forceinline__ void merge8(const ull* a, const ull* b, ull* m) {
#pragma unroll
  for (int t = 0; t < 8; ++t) { ull x = a[t], y = b[7 - t]; m[t] = x < y ? x : y; }
  CEX(m, 0, 4) CEX(m, 1, 5) CEX(m, 2, 6) CEX(m, 3, 7)
  CEX(m, 0, 2) CEX(m, 1, 3) CEX(m, 4, 6) CEX(m, 5, 7)
  CEX(m, 0, 1) CEX(m, 2, 3) CEX(m, 4, 5) CEX(m, 6, 7)
}

// -------- f32 -> bf16 --------
__global__ __launch_bounds__(256) void k_convert(
    const float* __restrict__ x, ushort* __restrict__ hi, int n4) {
  int i = blockIdx.x * 256 + threadIdx.x;
  if (i >= n4) return;
  float4 v = reinterpret_cast<const float4*>(x)[i];
  ushort4 h;
  h.x = f2bf(v.x); h.y = f2bf(v.y); h.z = f2bf(v.z); h.w = f2bf(v.w);
  reinterpret_cast<ushort4*>(hi)[i] = h;
}

// -------- bf16 MFMA GEMM: M[m][n] = bf16(exp(dot/EPS)); S += colsum (v==1) --------
__global__ __launch_bounds__(256) void k_gemm(
    const ushort* __restrict__ A_g, const ushort* __restrict__ B_g,
    ushort* __restrict__ M, float* __restrict__ S) {
  __shared__ ushort Ah[128][40], Bh[128][40];
  const int tid  = threadIdx.x;
  const int bn0  = blockIdx.x * 128;
  const int bm0  = blockIdx.y * 128;
  const int wid  = tid >> 6, lane = tid & 63;
  const int wm0  = (wid >> 1) * 64, wn0 = (wid & 1) * 64;
  const int ln15 = lane & 15, lq = lane >> 4;
  const int lr   = tid >> 2;
  const int lc   = (tid & 3) * 8;

  f32x4 acc[4][4] = {};

  for (int kk = 0; kk < DIM; kk += 32) {
#pragma unroll
    for (int p = 0; p < 2; ++p) {
      int row = p * 64 + lr;
      size_t ga = (size_t)(bm0 + row) * DIM + kk + lc;
      int brow = bn0 + row; if (brow >= K) brow = K - 1;
      size_t gb = (size_t)brow * DIM + kk + lc;
      *reinterpret_cast<bf16x8*>(&Ah[row][lc]) = *reinterpret_cast<const bf16x8*>(&A_g[ga]);
      *reinterpret_cast<bf16x8*>(&Bh[row][lc]) = *reinterpret_cast<const bf16x8*>(&B_g[gb]);
    }
    __syncthreads();
    bf16x8 ah[4], bh[4];
#pragma unroll
    for (int i = 0; i < 4; ++i) {
      ah[i] = *reinterpret_cast<const bf16x8*>(&Ah[wm0 + i * 16 + ln15][lq * 8]);
      bh[i] = *reinterpret_cast<const bf16x8*>(&Bh[wn0 + i * 16 + ln15][lq * 8]);
    }
#pragma unroll
    for (int i = 0; i < 4; ++i)
#pragma unroll
      for (int j = 0; j < 4; ++j)
        acc[i][j] = __builtin_amdgcn_mfma_f32_16x16x32_bf16(ah[i], bh[j], acc[i][j], 0, 0, 0);
    __syncthreads();
  }

#pragma unroll
  for (int j = 0; j < 4; ++j) {
    int col = bn0 + wn0 + j * 16 + ln15;
    bool valid = col < K;
    bool inmat = col < KP;
    float csum = 0.f;
#pragma unroll
    for (int i = 0; i < 4; ++i) {
      int rowb = bm0 + wm0 + i * 16 + lq * 4;
#pragma unroll
      for (int r = 0; r < 4; ++r) {
        float q = valid ? expf(acc[i][j][r] * INV_EPS) : 0.f;
        if (inmat) M[(size_t)(rowb + r) * KP + col] = f2bf(q);
        csum += q;
      }
    }
    csum += __shfl_xor(csum, 16, 64);
    csum += __shfl_xor(csum, 32, 64);
    if (lane < 16 && valid) atomicAdd(&S[col], csum);
  }
}

// -------- sample rows: exp -> bf16 matrix rows + v0-colsum into S --------
__global__ __launch_bounds__(256) void k_initsample(
    const float* __restrict__ outCrop, ushort* __restrict__ M, float* __restrict__ S) {
  int k4 = blockIdx.x * 256 + threadIdx.x;
  if (k4 >= KP4) return;
  bool pad = k4 >= K4;
  int r0 = blockIdx.y * 16;
  float ax = 0.f, ay = 0.f, az = 0.f, aw = 0.f;
  for (int rr = 0; rr < 16; ++rr) {
    int row = r0 + rr;
    ushort4 w = make_ushort4(0, 0, 0, 0);
    if (!pad) {
      float4 x = reinterpret_cast<const float4*>(outCrop + (size_t)row * K)[k4];
      float ex = expf(x.x * INV_EPS), ey = expf(x.y * INV_EPS),
            ez = expf(x.z * INV_EPS), ew = expf(x.w * INV_EPS);
      ax += ex; ay += ey; az += ez; aw += ew;
      w.x = f2bf(ex); w.y = f2bf(ey); w.z = f2bf(ez); w.w = f2bf(ew);
    }
    reinterpret_cast<ushort4*>(M + (size_t)(QL + row) * KP)[k4] = w;
  }
  if (!pad) {
    atomicAdd(&S[k4 * 4 + 0], ax);
    atomicAdd(&S[k4 * 4 + 1], ay);
    atomicAdd(&S[k4 * 4 + 2], az);
    atomicAdd(&S[k4 * 4 + 3], aw);
  }
}

// -------- rowpass: v[n] = 1/(NTOT * sum_k M[n][k]/(K*S_in[k])) --------
__global__ __launch_bounds__(256) void k_rowpass(
    const ushort* __restrict__ M, const float* __restrict__ S_in, float* __restrict__ v) {
  __shared__ float red[4];
  const int tid = threadIdx.x;
  const int n = blockIdx.x;
  const ushort* row = M + (size_t)n * KP;
  const int g1 = tid, g2 = tid + 256;
  const bool has2 = g2 < KP / 8;
  const bool pad2 = has2 && (g2 == 375);

  float ua[8], ub[8];
  {
    float4 s0 = reinterpret_cast<const float4*>(S_in)[g1 * 2];
    float4 s1 = reinterpret_cast<const float4*>(S_in)[g1 * 2 + 1];
    ua[0] = 1.0f / (KF * s0.x); ua[1] = 1.0f / (KF * s0.y);
    ua[2] = 1.0f / (KF * s0.z); ua[3] = 1.0f / (KF * s0.w);
    ua[4] = 1.0f / (KF * s1.x); ua[5] = 1.0f / (KF * s1.y);
    ua[6] = 1.0f / (KF * s1.z); ua[7] = 1.0f / (KF * s1.w);
  }
  if (has2 && !pad2) {
    float4 s0 = reinterpret_cast<const float4*>(S_in)[g2 * 2];
    float4 s1 = reinterpret_cast<const float4*>(S_in)[g2 * 2 + 1];
    ub[0] = 1.0f / (KF * s0.x); ub[1] = 1.0f / (KF * s0.y);
    ub[2] = 1.0f / (KF * s0.z); ub[3] = 1.0f / (KF * s0.w);
    ub[4] = 1.0f / (KF * s1.x); ub[5] = 1.0f / (KF * s1.y);
    ub[6] = 1.0f / (KF * s1.z); ub[7] = 1.0f / (KF * s1.w);
  } else {
#pragma unroll
    for (int e = 0; e < 8; ++e) ub[e] = 0.f;
  }

  float s = 0.f;
  {
    bf16x8 a = *reinterpret_cast<const bf16x8*>(&row[g1 * 8]);
#pragma unroll
    for (int e = 0; e < 8; ++e) s += bf2f(a[e]) * ua[e];
    if (has2) {
      bf16x8 c = *reinterpret_cast<const bf16x8*>(&row[g2 * 8]);
#pragma unroll
      for (int e = 0; e < 8; ++e) s += bf2f(c[e]) * ub[e];
    }
  }
  s = wave_sum(s);
  if ((tid & 63) == 0) red[tid >> 6] = s;
  __syncthreads();
  if (tid == 0) v[n] = 1.0f / ((float)NTOT * (red[0] + red[1] + red[2] + red[3]));
}

// -------- colsum: S_out[k] = sum_n M[n][k]*v[n] --------
__global__ __launch_bounds__(256) void k_colsum(
    const ushort* __restrict__ M, const float* __restrict__ v, float* __restrict__ S_out) {
  __shared__ float vsh[32];
  const int tid = threadIdx.x;
  const int g = blockIdx.x * 256 + tid;
  const int n0 = blockIdx.y * 32;
  if (tid < 32) vsh[tid] = v[n0 + tid];
  __syncthreads();
  if (g >= KP4) return;
  float c0 = 0.f, c1 = 0.f, c2 = 0.f, c3 = 0.f;
#pragma unroll 8
  for (int rr = 0; rr < 32; ++rr) {
    ushort4 m = reinterpret_cast<const ushort4*>(M + (size_t)(n0 + rr) * KP)[g];
    float vr = vsh[rr];
    c0 += bf2f((short)m.x) * vr;
    c1 += bf2f((short)m.y) * vr;
    c2 += bf2f((short)m.z) * vr;
    c3 += bf2f((short)m.w) * vr;
  }
  atomicAdd(&S_out[g * 4 + 0], c0);
  atomicAdd(&S_out[g * 4 + 1], c1);
  atomicAdd(&S_out[g * 4 + 2], c2);
  atomicAdd(&S_out[g * 4 + 3], c3);
}

// -------- logu[k] = -log(K * S3[k]) --------
__global__ __launch_bounds__(256) void k_logu(
    const float* __restrict__ S3, float* __restrict__ logu) {
  int k4 = blockIdx.x * 256 + threadIdx.x;
  if (k4 >= K4) return;
  float4 s = reinterpret_cast<const float4*>(S3)[k4];
  float4 r;
  r.x = -logf(KF * s.x); r.y = -logf(KF * s.y);
  r.z = -logf(KF * s.z); r.w = -logf(KF * s.w);
  reinterpret_cast<float4*>(logu)[k4] = r;
}

// -------- per sample row: hard_q, neg_q (log-domain keys), crop-1 cc term --------
__global__ __launch_bounds__(256) void k_stats(
    const float* __restrict__ outputAll, const float* __restrict__ logu,
    int crop, int* __restrict__ hardq, int* __restrict__ negq,
    float* __restrict__ accum) {
  __shared__ ull sml[4][8];
  __shared__ ull sm4[4];
  __shared__ float red[4][4];
  const int tid = threadIdx.x;
  const int lane = tid & 63, wid = tid >> 6;
  const int j = blockIdx.x;
  const float* orow = outputAll + (size_t)(crop * BS + j) * K;
  const bool val2 = tid < (K4 - 512);   // tid < 238

  float4 o0 = reinterpret_cast<const float4*>(orow)[tid];
  float4 o1 = reinterpret_cast<const float4*>(orow)[tid + 256];
  float4 o2 = val2 ? reinterpret_cast<const float4*>(orow)[tid + 512] : make_float4(0, 0, 0, 0);
  float4 l0 = reinterpret_cast<const float4*>(logu)[tid];
  float4 l1 = reinterpret_cast<const float4*>(logu)[tid + 256];
  float4 l2 = val2 ? reinterpret_cast<const float4*>(logu)[tid + 512] : make_float4(0, 0, 0, 0);

  float r[12];
  r[0] = o0.x * INV_EPS + l0.x;  r[1] = o0.y * INV_EPS + l0.y;
  r[2] = o0.z * INV_EPS + l0.z;  r[3] = o0.w * INV_EPS + l0.w;
  r[4] = o1.x * INV_EPS + l1.x;  r[5] = o1.y * INV_EPS + l1.y;
  r[6] = o1.z * INV_EPS + l1.z;  r[7] = o1.w * INV_EPS + l1.w;
  r[8] = o2.x * INV_EPS + l2.x;  r[9] = o2.y * INV_EPS + l2.y;
  r[10] = o2.z * INV_EPS + l2.z; r[11] = o2.w * INV_EPS + l2.w;

  ull am = 0ull;
  ull best[8];
#pragma unroll
  for (int t = 0; t < 8; ++t) best[t] = ~0ull;
#pragma unroll
  for (int e = 0; e < 12; ++e) {
    bool valid = (e < 8) || val2;
    if (valid) {
      int k = (tid + (e >> 2) * 256) * 4 + (e & 3);
      unsigned int mono = fmono(r[e]);
      ull pa = ((ull)mono << 32) | (unsigned int)(~k);
      am = pa > am ? pa : am;
      ull pb = ((ull)mono << 32) | (unsigned int)k;
      if (pb < best[7]) {
        best[7] = pb;
#pragma unroll
        for (int t = 7; t > 0; --t)
          if (best[t] < best[t - 1]) { ull tmp = best[t]; best[t] = best[t - 1]; best[t - 1] = tmp; }
      }
    }
  }

  // wave butterfly merge (all lanes end with wave bottom-8)
#pragma unroll
  for (int off = 1; off < 64; off <<= 1) {
    ull b[8], m[8];
#pragma unroll
    for (int t = 0; t < 8; ++t) b[t] = __shfl_xor(best[t], off, 64);
    merge8(best, b, m);
#pragma unroll
    for (int t = 0; t < 8; ++t) best[t] = m[t];
  }
  am = wave_maxu64(am);
  if (lane == 0) {
    sm4[wid] = am;
#pragma unroll
    for (int t = 0; t < 8; ++t) sml[wid][t] = best[t];
  }
  __syncthreads();
  if (tid == 0) {
    ull amx = sm4[0];
#pragma unroll
    for (int t = 1; t < 4; ++t) amx = sm4[t] > amx ? sm4[t] : amx;
    hardq[crop * BS + j] = (int)(~(unsigned int)(amx & 0xffffffffull));
    ull ma[8], mb[8], mf[8];
    merge8(sml[0], sml[1], ma);
    merge8(sml[2], sml[3], mb);
    merge8(ma, mb, mf);
#pragma unroll
    for (int t = 0; t < 6; ++t)
      negq[(size_t)(crop * BS + j) * 6 + t] = (int)(unsigned int)(mf[2 + t] & 0xffffffffull);
  }

  if (crop == 1) {
    const float* xrow = outputAll + (size_t)j * K;
    float4 x0 = reinterpret_cast<const float4*>(xrow)[tid];
    float4 x1 = reinterpret_cast<const float4*>(xrow)[tid + 256];
    float4 x2 = val2 ? reinterpret_cast<const float4*>(xrow)[tid + 512] : make_float4(0, 0, 0, 0);
    float x[12];
    x[0] = x0.x; x[1] = x0.y; x[2] = x0.z; x[3] = x0.w;
    x[4] = x1.x; x[5] = x1.y; x[6] = x1.z; x[7] = x1.w;
    x[8] = x2.x; x[9] = x2.y; x[10] = x2.z; x[11] = x2.w;

    float mx = -3.4e38f;
#pragma unroll
    for (int e = 0; e < 12; ++e) {
      bool valid = (e < 8) || val2;
      if (valid) mx = fmaxf(mx, x[e]);
    }
    mx = wave_max(mx);
    if (lane == 0) red[0][wid] = mx;
    __syncthreads();
    mx = fmaxf(fmaxf(red[0][0], red[0][1]), fmaxf(red[0][2], red[0][3]));

    float sk = 0.f, skx = 0.f, se = 0.f;
#pragma unroll
    for (int e = 0; e < 12; ++e) {
      bool valid = (e < 8) || val2;
      if (valid) {
        float q = expf(r[e]);
        sk += q;
        skx += q * x[e];
        se += expf((x[e] - mx) * 5.0f);
      }
    }
    sk = wave_sum(sk); skx = wave_sum(skx); se = wave_sum(se);
    if (lane == 0) { red[1][wid] = sk; red[2][wid] = skx; red[3][wid] = se; }
    __syncthreads();
    if (tid == 0) {
      float SK  = red[1][0] + red[1][1] + red[1][2] + red[1][3];
      float SKX = red[2][0] + red[2][1] + red[2][2] + red[2][3];
      float SE  = red[3][0] + red[3][1] + red[3][2] + red[3][3];
      float lse = mx * 5.0f + logf(SE);
      atomicAdd(&accum[2], SKX * 5.0f / SK - lse);
    }
  }
}

// -------- normalize both pair rows + pos dot --------
__global__ __launch_bounds__(256) void k_normpos(
    const float* __restrict__ emb, float* __restrict__ outc, float* __restrict__ accum) {
  __shared__ float sa[4], sb[4], sd[4];
  __shared__ float na, nb;
  const int j = blockIdx.x, t = threadIdx.x;
  float za = emb[(size_t)(BS + j) * DIM + t] / TEMP;  // -> outc[j]
  float zb = emb[(size_t)j * DIM + t] / TEMP;         // -> outc[BS+j]
  float ra = wave_sum(za * za);
  float rb = wave_sum(zb * zb);
  if ((t & 63) == 0) { sa[t >> 6] = ra; sb[t >> 6] = rb; }
  __syncthreads();
  if (t == 0) {
    na = sqrtf(sa[0] + sa[1] + sa[2] + sa[3]);
    nb = sqrtf(sb[0] + sb[1] + sb[2] + sb[3]);
  }
  __syncthreads();
  float oa = za / na, ob = zb / nb;
  outc[(size_t)j * DIM + t] = oa;
  outc[(size_t)(BS + j) * DIM + t] = ob;
  float d = wave_sum(oa * ob);
  if ((t & 63) == 0) sd[t >> 6] = d;
  __syncthreads();
  if (t == 0) atomicAdd(&accum[1], sd[0] + sd[1] + sd[2] + sd[3]);
}

// -------- denom via class histogram --------
__global__ __launch_bounds__(256) void k_hist(
    const int* __restrict__ hardq, int* __restrict__ cnt) {
  int j = blockIdx.x * 256 + threadIdx.x;
  atomicAdd(&cnt[hardq[j]], 1);
}

__global__ __launch_bounds__(256) void k_scan(
    const int* __restrict__ cnt, int* __restrict__ offa) {
  __shared__ int wsum[4];
  __shared__ int wpre[4];
  const int tid = threadIdx.x;
  const int lane = tid & 63, wid = tid >> 6;
  const int base = tid * 12;
  int loc[12];
  int s = 0;
#pragma unroll
  for (int t = 0; t < 12; ++t) {
    int idx = base + t;
    int cv = (idx < K) ? cnt[idx] : 0;
    loc[t] = cv; s += cv;
  }
  int vincl = s;
#pragma unroll
  for (int d = 1; d < 64; d <<= 1) {
    int t = __shfl_up(vincl, d, 64);
    if (lane >= d) vincl += t;
  }
  if (lane == 63) wsum[wid] = vincl;
  __syncthreads();
  if (tid == 0) {
    int r = 0;
#pragma unroll
    for (int w = 0; w < 4; ++w) { wpre[w] = r; r += wsum[w]; }
  }
  __syncthreads();
  int run = vincl - s + wpre[wid];
#pragma unroll
  for (int t = 0; t < 12; ++t) {
    int idx = base + t;
    if (idx < K) { offa[idx] = run; run += loc[t]; }
  }
  if (tid == 255) offa[K] = run;
}

__global__ __launch_bounds__(256) void k_scatter(
    const int* __restrict__ hardq, const int* __restrict__ offa,
    int* __restrict__ cur, int* __restrict__ bucket) {
  int j = blockIdx.x * 256 + threadIdx.x;
  int c = hardq[j];
  int p = atomicAdd(&cur[c], 1);
  bucket[offa[c] + p] = j;
}

__global__ __launch_bounds__(256) void k_denom2(
    const float* __restrict__ outc, const int* __restrict__ negq,
    const int* __restrict__ offa, const int* __restrict__ bucket,
    float* __restrict__ partial) {
  __shared__ float s4[4];
  const int tid = threadIdx.x;
  const int wid = tid >> 6, lane = tid & 63;
  const int task = blockIdx.x * 4 + wid;
  const int i = task / 6, slot = task - i * 6;
  const int c = negq[i * 6 + slot];
  const int lo = offa[c];
  const int n = offa[c + 1] - lo;
  float acc = 0.f;
  if (n > 0) {
    const float4 a = reinterpret_cast<const float4*>(outc + (size_t)i * DIM)[lane];
    for (int m = 0; m < n; ++m) {
      int j = bucket[lo + m];
      if (j == i) continue;
      const float4 b = reinterpret_cast<const float4*>(outc + (size_t)j * DIM)[lane];
      float d = a.x * b.x + a.y * b.y + a.z * b.z + a.w * b.w;
      d = wave_sum(d);
      if (lane == 0) acc += expf(d * 5.0f);
    }
  }
  if (lane == 0) s4[wid] = acc;
  __syncthreads();
  if (tid == 0) partial[blockIdx.x] = s4[0] + s4[1] + s4[2] + s4[3];
}

__global__ __launch_bounds__(256) void k_final(
    const float* __restrict__ accum, const float* __restrict__ partial,
    float* __restrict__ out) {
  __shared__ float s4[4];
  const int tid = threadIdx.x;
  float s = 0.f;
  for (int m = tid; m < NDBLK; m += 256) s += partial[m];
  s = wave_sum(s);
  if ((tid & 63) == 0) s4[tid >> 6] = s;
  __syncthreads();
  if (tid == 0) {
    float denom = s4[0] + s4[1] + s4[2] + s4[3];
    float possum = accum[1];
    float ccsum  = accum[2];
    float contrast = logf(denom) - possum / ((float)BS * TEMP);
    out[0] = contrast - 6.0f * ccsum / (float)BS;
  }
}

}  // namespace

extern "C" void kernel_launch(void* const* d_in, const int* in_sizes, int n_in,
                              void* d_out, int out_size, void* d_ws, size_t ws_size,
                              hipStream_t stream) {
  const float* queue  = (const float*)d_in[3];  // [2][QL][DIM]
  const float* proto  = (const float*)d_in[4];  // [K][DIM]
  const float* output = (const float*)d_in[5];  // [2*BS][K]
  const float* emb    = (const float*)d_in[6];  // [2*BS][DIM]
  float* ws = (float*)d_ws;
  ushort* M    = (ushort*)(ws + OFF_M);
  float* S     = ws + OFF_S;
  float* accum = ws + OFF_ACC;
  int* cnt     = (int*)(ws + OFF_CNT);
  int* offa    = (int*)(ws + OFF_OFFA);
  int* cur     = (int*)(ws + OFF_CUR);
  float* v     = ws + OFF_V;
  int* hardq   = (int*)(ws + OFF_HQ);
  int* negq    = (int*)(ws + OFF_NQ);
  float* logu  = ws + OFF_LOGU;
  int* bucket  = (int*)(ws + OFF_BUCKET);
  float* partial = ws + OFF_PART;
  ushort* cvt  = (ushort*)(ws + OFF_CVT);
  float* outc  = ws + OFF_OUTC;
  float* out   = (float*)d_out;

  // single fused zero: S(6KP) + accum(8) + cnt(3008) + offa(3072) + cur(3008)
  hipMemsetAsync(S, 0, (6 * KP + 8 + 3008 + 3072 + 3008) * sizeof(float), stream);

  {
    int n4q = 2 * QL * DIM / 4;
    k_convert<<<(n4q + 255) / 256, 256, 0, stream>>>(queue, cvt, n4q);
    int n4p = K * DIM / 4;
    k_convert<<<(n4p + 255) / 256, 256, 0, stream>>>(proto, cvt + (size_t)2 * QL * DIM, n4p);
  }

  for (int crop = 0; crop < 2; ++crop) {
    const float* ocrop = output + (size_t)crop * BS * K;
    const ushort* A = cvt + (size_t)crop * QL * DIM;
    const ushort* B = cvt + (size_t)2 * QL * DIM;
    float* S1 = S + (size_t)crop * 3 * KP;
    float* S2 = S1 + KP;
    float* S3 = S1 + 2 * KP;

    k_gemm<<<dim3((K + 127) / 128, QL / 128), 256, 0, stream>>>(A, B, M, S1);
    k_initsample<<<dim3((KP4 + 255) / 256, BS / 16), 256, 0, stream>>>(ocrop, M, S1);
    k_rowpass<<<NTOT, 256, 0, stream>>>(M, S1, v);
    k_colsum<<<dim3(3, NTOT / 32), 256, 0, stream>>>(M, v, S2);
    k_rowpass<<<NTOT, 256, 0, stream>>>(M, S2, v);
    k_colsum<<<dim3(3, NTOT / 32), 256, 0, stream>>>(M, v, S3);
    k_logu<<<3, 256, 0, stream>>>(S3, logu);
    k_stats<<<BS, 256, 0, stream>>>(output, logu, crop, hardq, negq, accum);
  }

  k_normpos<<<BS, 256, 0, stream>>>(emb, outc, accum);
  k_hist<<<N2 / 256, 256, 0, stream>>>(hardq, cnt);
  k_scan<<<1, 256, 0, stream>>>(cnt, offa);
  k_scatter<<<N2 / 256, 256, 0, stream>>>(hardq, offa, cur, bucket);
  k_denom2<<<NDBLK, 256, 0, stream>>>(outc, negq, offa, bucket, partial);
  k_final<<<1, 256, 0, stream>>>(accum, partial, out);
}

// Round 6
// 341.469 us; speedup vs baseline: 2.2251x; 1.0386x over previous
//
#include <hip/hip_runtime.h>
#include <hip/hip_bf16.h>
#include <cstdint>

namespace {

constexpr int BS   = 2048;
constexpr int DIM  = 256;
constexpr int K    = 3000;
constexpr int K4   = K / 4;        // 750
constexpr int KP   = 3008;         // padded row stride (bf16 matrix)
constexpr int KP4  = KP / 4;       // 752
constexpr int QL   = 3840;
constexpr int NTOT = QL + BS;      // 5888
constexpr int N2   = 2 * BS;       // 4096
constexpr int NDBLK = N2 * 6 / 4;  // 6144
constexpr float TEMP = 0.2f;
constexpr float INV_EPS = 20.0f;
constexpr float KF = 3000.0f;

// ws layout (float indices)
constexpr size_t OFF_M    = 0;                              // NTOT*KP/2
constexpr size_t OFF_S    = OFF_M + (size_t)NTOT * KP / 2;  // 6*KP (S1..S3 x2 crops)
constexpr size_t OFF_ACC  = OFF_S + 6 * KP;                 // 8
constexpr size_t OFF_CNT  = OFF_ACC + 8;                    // 3008 ints
constexpr size_t OFF_OFFA = OFF_CNT + 3008;                 // 3072 ints
constexpr size_t OFF_CUR  = OFF_OFFA + 3072;                // 3008 ints
constexpr size_t OFF_V    = OFF_CUR + 3008;                 // NTOT
constexpr size_t OFF_HQ   = OFF_V + NTOT;                   // N2 ints
constexpr size_t OFF_NQ   = OFF_HQ + N2;                    // N2*6 ints
constexpr size_t OFF_LOGU = OFF_NQ + (size_t)N2 * 6;        // 3008
constexpr size_t OFF_BUCKET = OFF_LOGU + 3008;              // N2 ints
constexpr size_t OFF_PART = OFF_BUCKET + N2;                // NDBLK
constexpr size_t OFF_CVT  = ((OFF_PART + NDBLK + 15) / 16) * 16;
constexpr size_t OFF_OUTC = OFF_CVT;                        // reuse after GEMMs

using bf16x8 = __attribute__((ext_vector_type(8))) short;
using f32x4  = __attribute__((ext_vector_type(4))) float;
typedef unsigned long long ull;

__device__ __forceinline__ float wave_sum(float v) {
#pragma unroll
  for (int off = 32; off > 0; off >>= 1) v += __shfl_down(v, off, 64);
  return v;
}
__device__ __forceinline__ float wave_max(float v) {
#pragma unroll
  for (int off = 32; off > 0; off >>= 1) v = fmaxf(v, __shfl_down(v, off, 64));
  return v;
}
__device__ __forceinline__ ull wave_maxu64(ull v) {
#pragma unroll
  for (int off = 32; off > 0; off >>= 1) {
    ull o = __shfl_down(v, off, 64);
    v = (o > v) ? o : v;
  }
  return v;
}
__device__ __forceinline__ ull wave_minu64_all(ull v) {
#pragma unroll
  for (int off = 32; off > 0; off >>= 1) {
    ull o = __shfl_xor(v, off, 64);
    v = (o < v) ? o : v;
  }
  return v;
}
__device__ __forceinline__ unsigned int fmono(float f) {
  unsigned int u = __float_as_uint(f);
  return (u & 0x80000000u) ? ~u : (u | 0x80000000u);
}
__device__ __forceinline__ float bf2f(short s) {
  return __uint_as_float(((unsigned int)(unsigned short)s) << 16);
}
__device__ __forceinline__ ushort f2bf(float f) {
  __hip_bfloat16 b = __float2bfloat16(f);
  return *reinterpret_cast<ushort*>(&b);
}

// -------- f32 -> bf16 --------
__global__ __launch_bounds__(256) void k_convert(
    const float* __restrict__ x, ushort* __restrict__ hi, int n4) {
  int i = blockIdx.x * 256 + threadIdx.x;
  if (i >= n4) return;
  float4 v = reinterpret_cast<const float4*>(x)[i];
  ushort4 h;
  h.x = f2bf(v.x); h.y = f2bf(v.y); h.z = f2bf(v.z); h.w = f2bf(v.w);
  reinterpret_cast<ushort4*>(hi)[i] = h;
}

// -------- bf16 MFMA GEMM: M[m][n] = bf16(exp(dot/EPS)); S += colsum (v==1) --------
__global__ __launch_bounds__(256) void k_gemm(
    const ushort* __restrict__ A_g, const ushort* __restrict__ B_g,
    ushort* __restrict__ M, float* __restrict__ S) {
  __shared__ ushort Ah[128][40], Bh[128][40];
  const int tid  = threadIdx.x;
  const int bn0  = blockIdx.x * 128;
  const int bm0  = blockIdx.y * 128;
  const int wid  = tid >> 6, lane = tid & 63;
  const int wm0  = (wid >> 1) * 64, wn0 = (wid & 1) * 64;
  const int ln15 = lane & 15, lq = lane >> 4;
  const int lr   = tid >> 2;
  const int lc   = (tid & 3) * 8;

  f32x4 acc[4][4] = {};

  for (int kk = 0; kk < DIM; kk += 32) {
#pragma unroll
    for (int p = 0; p < 2; ++p) {
      int row = p * 64 + lr;
      size_t ga = (size_t)(bm0 + row) * DIM + kk + lc;
      int brow = bn0 + row; if (brow >= K) brow = K - 1;
      size_t gb = (size_t)brow * DIM + kk + lc;
      *reinterpret_cast<bf16x8*>(&Ah[row][lc]) = *reinterpret_cast<const bf16x8*>(&A_g[ga]);
      *reinterpret_cast<bf16x8*>(&Bh[row][lc]) = *reinterpret_cast<const bf16x8*>(&B_g[gb]);
    }
    __syncthreads();
    bf16x8 ah[4], bh[4];
#pragma unroll
    for (int i = 0; i < 4; ++i) {
      ah[i] = *reinterpret_cast<const bf16x8*>(&Ah[wm0 + i * 16 + ln15][lq * 8]);
      bh[i] = *reinterpret_cast<const bf16x8*>(&Bh[wn0 + i * 16 + ln15][lq * 8]);
    }
#pragma unroll
    for (int i = 0; i < 4; ++i)
#pragma unroll
      for (int j = 0; j < 4; ++j)
        acc[i][j] = __builtin_amdgcn_mfma_f32_16x16x32_bf16(ah[i], bh[j], acc[i][j], 0, 0, 0);
    __syncthreads();
  }

#pragma unroll
  for (int j = 0; j < 4; ++j) {
    int col = bn0 + wn0 + j * 16 + ln15;
    bool valid = col < K;
    bool inmat = col < KP;
    float csum = 0.f;
#pragma unroll
    for (int i = 0; i < 4; ++i) {
      int rowb = bm0 + wm0 + i * 16 + lq * 4;
#pragma unroll
      for (int r = 0; r < 4; ++r) {
        float q = valid ? __expf(acc[i][j][r] * INV_EPS) : 0.f;
        if (inmat) M[(size_t)(rowb + r) * KP + col] = f2bf(q);
        csum += q;
      }
    }
    csum += __shfl_xor(csum, 16, 64);
    csum += __shfl_xor(csum, 32, 64);
    if (lane < 16 && valid) atomicAdd(&S[col], csum);
  }
}

// -------- sample rows: exp -> bf16 matrix rows + v0-colsum into S --------
__global__ __launch_bounds__(256) void k_initsample(
    const float* __restrict__ outCrop, ushort* __restrict__ M, float* __restrict__ S) {
  int k4 = blockIdx.x * 256 + threadIdx.x;
  if (k4 >= KP4) return;
  bool pad = k4 >= K4;
  int r0 = blockIdx.y * 16;
  float ax = 0.f, ay = 0.f, az = 0.f, aw = 0.f;
  for (int rr = 0; rr < 16; ++rr) {
    int row = r0 + rr;
    ushort4 w = make_ushort4(0, 0, 0, 0);
    if (!pad) {
      float4 x = reinterpret_cast<const float4*>(outCrop + (size_t)row * K)[k4];
      float ex = __expf(x.x * INV_EPS), ey = __expf(x.y * INV_EPS),
            ez = __expf(x.z * INV_EPS), ew = __expf(x.w * INV_EPS);
      ax += ex; ay += ey; az += ez; aw += ew;
      w.x = f2bf(ex); w.y = f2bf(ey); w.z = f2bf(ez); w.w = f2bf(ew);
    }
    reinterpret_cast<ushort4*>(M + (size_t)(QL + row) * KP)[k4] = w;
  }
  if (!pad) {
    atomicAdd(&S[k4 * 4 + 0], ax);
    atomicAdd(&S[k4 * 4 + 1], ay);
    atomicAdd(&S[k4 * 4 + 2], az);
    atomicAdd(&S[k4 * 4 + 3], aw);
  }
}

// -------- rowpass: v[n] = 1/(NTOT * sum_k M[n][k]/(K*S_in[k])) --------
__global__ __launch_bounds__(256) void k_rowpass(
    const ushort* __restrict__ M, const float* __restrict__ S_in, float* __restrict__ v) {
  __shared__ float red[4];
  const int tid = threadIdx.x;
  const int n = blockIdx.x;
  const ushort* row = M + (size_t)n * KP;
  const int g1 = tid, g2 = tid + 256;
  const bool has2 = g2 < KP / 8;
  const bool pad2 = has2 && (g2 == 375);

  float ua[8], ub[8];
  {
    float4 s0 = reinterpret_cast<const float4*>(S_in)[g1 * 2];
    float4 s1 = reinterpret_cast<const float4*>(S_in)[g1 * 2 + 1];
    ua[0] = 1.0f / (KF * s0.x); ua[1] = 1.0f / (KF * s0.y);
    ua[2] = 1.0f / (KF * s0.z); ua[3] = 1.0f / (KF * s0.w);
    ua[4] = 1.0f / (KF * s1.x); ua[5] = 1.0f / (KF * s1.y);
    ua[6] = 1.0f / (KF * s1.z); ua[7] = 1.0f / (KF * s1.w);
  }
  if (has2 && !pad2) {
    float4 s0 = reinterpret_cast<const float4*>(S_in)[g2 * 2];
    float4 s1 = reinterpret_cast<const float4*>(S_in)[g2 * 2 + 1];
    ub[0] = 1.0f / (KF * s0.x); ub[1] = 1.0f / (KF * s0.y);
    ub[2] = 1.0f / (KF * s0.z); ub[3] = 1.0f / (KF * s0.w);
    ub[4] = 1.0f / (KF * s1.x); ub[5] = 1.0f / (KF * s1.y);
    ub[6] = 1.0f / (KF * s1.z); ub[7] = 1.0f / (KF * s1.w);
  } else {
#pragma unroll
    for (int e = 0; e < 8; ++e) ub[e] = 0.f;
  }

  float s = 0.f;
  {
    bf16x8 a = *reinterpret_cast<const bf16x8*>(&row[g1 * 8]);
#pragma unroll
    for (int e = 0; e < 8; ++e) s += bf2f(a[e]) * ua[e];
    if (has2) {
      bf16x8 c = *reinterpret_cast<const bf16x8*>(&row[g2 * 8]);
#pragma unroll
      for (int e = 0; e < 8; ++e) s += bf2f(c[e]) * ub[e];
    }
  }
  s = wave_sum(s);
  if ((tid & 63) == 0) red[tid >> 6] = s;
  __syncthreads();
  if (tid == 0) v[n] = 1.0f / ((float)NTOT * (red[0] + red[1] + red[2] + red[3]));
}

// -------- colsum: S_out[k] = sum_n M[n][k]*v[n] --------
__global__ __launch_bounds__(256) void k_colsum(
    const ushort* __restrict__ M, const float* __restrict__ v, float* __restrict__ S_out) {
  __shared__ float vsh[32];
  const int tid = threadIdx.x;
  const int g = blockIdx.x * 256 + tid;
  const int n0 = blockIdx.y * 32;
  if (tid < 32) vsh[tid] = v[n0 + tid];
  __syncthreads();
  if (g >= KP4) return;
  float c0 = 0.f, c1 = 0.f, c2 = 0.f, c3 = 0.f;
#pragma unroll 8
  for (int rr = 0; rr < 32; ++rr) {
    ushort4 m = reinterpret_cast<const ushort4*>(M + (size_t)(n0 + rr) * KP)[g];
    float vr = vsh[rr];
    c0 += bf2f((short)m.x) * vr;
    c1 += bf2f((short)m.y) * vr;
    c2 += bf2f((short)m.z) * vr;
    c3 += bf2f((short)m.w) * vr;
  }
  atomicAdd(&S_out[g * 4 + 0], c0);
  atomicAdd(&S_out[g * 4 + 1], c1);
  atomicAdd(&S_out[g * 4 + 2], c2);
  atomicAdd(&S_out[g * 4 + 3], c3);
}

// -------- logu[k] = -log(K * S3[k]) --------
__global__ __launch_bounds__(256) void k_logu(
    const float* __restrict__ S3, float* __restrict__ logu) {
  int k4 = blockIdx.x * 256 + threadIdx.x;
  if (k4 >= K4) return;
  float4 s = reinterpret_cast<const float4*>(S3)[k4];
  float4 r;
  r.x = -__logf(KF * s.x); r.y = -__logf(KF * s.y);
  r.z = -__logf(KF * s.z); r.w = -__logf(KF * s.w);
  reinterpret_cast<float4*>(logu)[k4] = r;
}

// -------- per sample row: hard_q, neg_q (threshold-filtered exact bottom-8),
//          crop-1 cc term --------
template <int CROP>
__global__ __launch_bounds__(256) void k_stats(
    const float* __restrict__ outputAll, const float* __restrict__ logu,
    int* __restrict__ hardq, int* __restrict__ negq, float* __restrict__ accum) {
  __shared__ ull lmins[256];
  __shared__ ull cand[256];
  __shared__ ull sm4[4];
  __shared__ ull smf[8];
  __shared__ ull sT;
  __shared__ int scnt;
  __shared__ float red[4][4];
  const int tid = threadIdx.x;
  const int lane = tid & 63, wid = tid >> 6;
  const int j = blockIdx.x;
  const float* orow = outputAll + (size_t)(CROP * BS + j) * K;
  const bool val2 = tid < (K4 - 512);   // tid < 238

  float4 o0 = reinterpret_cast<const float4*>(orow)[tid];
  float4 o1 = reinterpret_cast<const float4*>(orow)[tid + 256];
  float4 o2 = val2 ? reinterpret_cast<const float4*>(orow)[tid + 512] : make_float4(0, 0, 0, 0);
  float4 l0 = reinterpret_cast<const float4*>(logu)[tid];
  float4 l1 = reinterpret_cast<const float4*>(logu)[tid + 256];
  float4 l2 = val2 ? reinterpret_cast<const float4*>(logu)[tid + 512] : make_float4(0, 0, 0, 0);

  float r[12];
  r[0] = o0.x * INV_EPS + l0.x;  r[1] = o0.y * INV_EPS + l0.y;
  r[2] = o0.z * INV_EPS + l0.z;  r[3] = o0.w * INV_EPS + l0.w;
  r[4] = o1.x * INV_EPS + l1.x;  r[5] = o1.y * INV_EPS + l1.y;
  r[6] = o1.z * INV_EPS + l1.z;  r[7] = o1.w * INV_EPS + l1.w;
  r[8] = o2.x * INV_EPS + l2.x;  r[9] = o2.y * INV_EPS + l2.y;
  r[10] = o2.z * INV_EPS + l2.z; r[11] = o2.w * INV_EPS + l2.w;

  // local min (ascending key: (mono, k)) and argmax key (mono, ~k)
  ull lmin = ~0ull;
  ull am = 0ull;
#pragma unroll
  for (int e = 0; e < 12; ++e) {
    bool valid = (e < 8) || val2;
    if (valid) {
      int k = (tid + (e >> 2) * 256) * 4 + (e & 3);
      unsigned int mono = fmono(r[e]);
      ull pb = ((ull)mono << 32) | (unsigned int)k;
      lmin = pb < lmin ? pb : lmin;
      ull pa = ((ull)mono << 32) | (unsigned int)(~k);
      am = pa > am ? pa : am;
    }
  }
  lmins[tid] = lmin;
  am = wave_maxu64(am);
  if (lane == 0) sm4[wid] = am;
  if (tid == 0) scnt = 0;
  __syncthreads();

  // wave 0: T = exact 8th smallest of the 256 per-thread mins
  if (wid == 0) {
    ull c0 = lmins[lane], c1 = lmins[lane + 64], c2 = lmins[lane + 128], c3 = lmins[lane + 192];
    ull wm = 0;
#pragma unroll
    for (int it = 0; it < 8; ++it) {
      ull m01 = c0 < c1 ? c0 : c1;
      ull m23 = c2 < c3 ? c2 : c3;
      ull mm = m01 < m23 ? m01 : m23;
      wm = wave_minu64_all(mm);
      if (c0 == wm) c0 = ~0ull;
      else if (c1 == wm) c1 = ~0ull;
      else if (c2 == wm) c2 = ~0ull;
      else if (c3 == wm) c3 = ~0ull;
    }
    if (lane == 0) sT = wm;
  }
  __syncthreads();
  const ull T = sT;

  // all threads: push candidates <= T (guaranteed superset of global bottom-8)
#pragma unroll
  for (int e = 0; e < 12; ++e) {
    bool valid = (e < 8) || val2;
    if (valid) {
      int k = (tid + (e >> 2) * 256) * 4 + (e & 3);
      ull pb = ((ull)fmono(r[e]) << 32) | (unsigned int)k;
      if (pb <= T) {
        int p = atomicAdd(&scnt, 1);
        if (p < 256) cand[p] = pb;
      }
    }
  }
  __syncthreads();

  // wave 0: exact bottom-8 of candidates
  if (wid == 0) {
    const int n = scnt < 256 ? scnt : 256;
    ull c0 = lane < n ? cand[lane] : ~0ull;
    ull c1 = lane + 64 < n ? cand[lane + 64] : ~0ull;
    ull c2 = lane + 128 < n ? cand[lane + 128] : ~0ull;
    ull c3 = lane + 192 < n ? cand[lane + 192] : ~0ull;
#pragma unroll
    for (int it = 0; it < 8; ++it) {
      ull m01 = c0 < c1 ? c0 : c1;
      ull m23 = c2 < c3 ? c2 : c3;
      ull mm = m01 < m23 ? m01 : m23;
      ull wm = wave_minu64_all(mm);
      if (lane == 0) smf[it] = wm;
      if (c0 == wm) c0 = ~0ull;
      else if (c1 == wm) c1 = ~0ull;
      else if (c2 == wm) c2 = ~0ull;
      else if (c3 == wm) c3 = ~0ull;
    }
  }
  __syncthreads();
  if (tid == 0) {
    ull amx = sm4[0];
#pragma unroll
    for (int t = 1; t < 4; ++t) amx = sm4[t] > amx ? sm4[t] : amx;
    hardq[CROP * BS + j] = (int)(~(unsigned int)(amx & 0xffffffffull));
#pragma unroll
    for (int t = 0; t < 6; ++t)
      negq[(size_t)(CROP * BS + j) * 6 + t] = (int)(unsigned int)(smf[2 + t] & 0xffffffffull);
  }

  if (CROP == 1) {
    const float* xrow = outputAll + (size_t)j * K;
    float4 x0 = reinterpret_cast<const float4*>(xrow)[tid];
    float4 x1 = reinterpret_cast<const float4*>(xrow)[tid + 256];
    float4 x2 = val2 ? reinterpret_cast<const float4*>(xrow)[tid + 512] : make_float4(0, 0, 0, 0);
    float x[12];
    x[0] = x0.x; x[1] = x0.y; x[2] = x0.z; x[3] = x0.w;
    x[4] = x1.x; x[5] = x1.y; x[6] = x1.z; x[7] = x1.w;
    x[8] = x2.x; x[9] = x2.y; x[10] = x2.z; x[11] = x2.w;

    float mx = -3.4e38f;
#pragma unroll
    for (int e = 0; e < 12; ++e) {
      bool valid = (e < 8) || val2;
      if (valid) mx = fmaxf(mx, x[e]);
    }
    mx = wave_max(mx);
    if (lane == 0) red[0][wid] = mx;
    __syncthreads();
    mx = fmaxf(fmaxf(red[0][0], red[0][1]), fmaxf(red[0][2], red[0][3]));

    float sk = 0.f, skx = 0.f, se = 0.f;
#pragma unroll
    for (int e = 0; e < 12; ++e) {
      bool valid = (e < 8) || val2;
      if (valid) {
        float q = __expf(r[e]);
        sk += q;
        skx += q * x[e];
        se += __expf((x[e] - mx) * 5.0f);
      }
    }
    sk = wave_sum(sk); skx = wave_sum(skx); se = wave_sum(se);
    if (lane == 0) { red[1][wid] = sk; red[2][wid] = skx; red[3][wid] = se; }
    __syncthreads();
    if (tid == 0) {
      float SK  = red[1][0] + red[1][1] + red[1][2] + red[1][3];
      float SKX = red[2][0] + red[2][1] + red[2][2] + red[2][3];
      float SE  = red[3][0] + red[3][1] + red[3][2] + red[3][3];
      float lse = mx * 5.0f + __logf(SE);
      atomicAdd(&accum[2], SKX * 5.0f / SK - lse);
    }
  }
}

// -------- normalize both pair rows + pos dot --------
__global__ __launch_bounds__(256) void k_normpos(
    const float* __restrict__ emb, float* __restrict__ outc, float* __restrict__ accum) {
  __shared__ float sa[4], sb[4], sd[4];
  __shared__ float na, nb;
  const int j = blockIdx.x, t = threadIdx.x;
  float za = emb[(size_t)(BS + j) * DIM + t] / TEMP;  // -> outc[j]
  float zb = emb[(size_t)j * DIM + t] / TEMP;         // -> outc[BS+j]
  float ra = wave_sum(za * za);
  float rb = wave_sum(zb * zb);
  if ((t & 63) == 0) { sa[t >> 6] = ra; sb[t >> 6] = rb; }
  __syncthreads();
  if (t == 0) {
    na = sqrtf(sa[0] + sa[1] + sa[2] + sa[3]);
    nb = sqrtf(sb[0] + sb[1] + sb[2] + sb[3]);
  }
  __syncthreads();
  float oa = za / na, ob = zb / nb;
  outc[(size_t)j * DIM + t] = oa;
  outc[(size_t)(BS + j) * DIM + t] = ob;
  float d = wave_sum(oa * ob);
  if ((t & 63) == 0) sd[t >> 6] = d;
  __syncthreads();
  if (t == 0) atomicAdd(&accum[1], sd[0] + sd[1] + sd[2] + sd[3]);
}

// -------- denom via class histogram --------
__global__ __launch_bounds__(256) void k_hist(
    const int* __restrict__ hardq, int* __restrict__ cnt) {
  int j = blockIdx.x * 256 + threadIdx.x;
  atomicAdd(&cnt[hardq[j]], 1);
}

__global__ __launch_bounds__(256) void k_scan(
    const int* __restrict__ cnt, int* __restrict__ offa) {
  __shared__ int wsum[4];
  __shared__ int wpre[4];
  const int tid = threadIdx.x;
  const int lane = tid & 63, wid = tid >> 6;
  const int base = tid * 12;
  int loc[12];
  int s = 0;
#pragma unroll
  for (int t = 0; t < 12; ++t) {
    int idx = base + t;
    int cv = (idx < K) ? cnt[idx] : 0;
    loc[t] = cv; s += cv;
  }
  int vincl = s;
#pragma unroll
  for (int d = 1; d < 64; d <<= 1) {
    int t = __shfl_up(vincl, d, 64);
    if (lane >= d) vincl += t;
  }
  if (lane == 63) wsum[wid] = vincl;
  __syncthreads();
  if (tid == 0) {
    int r = 0;
#pragma unroll
    for (int w = 0; w < 4; ++w) { wpre[w] = r; r += wsum[w]; }
  }
  __syncthreads();
  int run = vincl - s + wpre[wid];
#pragma unroll
  for (int t = 0; t < 12; ++t) {
    int idx = base + t;
    if (idx < K) { offa[idx] = run; run += loc[t]; }
  }
  if (tid == 255) offa[K] = run;
}

__global__ __launch_bounds__(256) void k_scatter(
    const int* __restrict__ hardq, const int* __restrict__ offa,
    int* __restrict__ cur, int* __restrict__ bucket) {
  int j = blockIdx.x * 256 + threadIdx.x;
  int c = hardq[j];
  int p = atomicAdd(&cur[c], 1);
  bucket[offa[c] + p] = j;
}

__global__ __launch_bounds__(256) void k_denom2(
    const float* __restrict__ outc, const int* __restrict__ negq,
    const int* __restrict__ offa, const int* __restrict__ bucket,
    float* __restrict__ partial) {
  __shared__ float s4[4];
  const int tid = threadIdx.x;
  const int wid = tid >> 6, lane = tid & 63;
  const int task = blockIdx.x * 4 + wid;
  const int i = task / 6, slot = task - i * 6;
  const int c = negq[i * 6 + slot];
  const int lo = offa[c];
  const int n = offa[c + 1] - lo;
  float acc = 0.f;
  if (n > 0) {
    const float4 a = reinterpret_cast<const float4*>(outc + (size_t)i * DIM)[lane];
    for (int m = 0; m < n; ++m) {
      int j = bucket[lo + m];
      if (j == i) continue;
      const float4 b = reinterpret_cast<const float4*>(outc + (size_t)j * DIM)[lane];
      float d = a.x * b.x + a.y * b.y + a.z * b.z + a.w * b.w;
      d = wave_sum(d);
      if (lane == 0) acc += __expf(d * 5.0f);
    }
  }
  if (lane == 0) s4[wid] = acc;
  __syncthreads();
  if (tid == 0) partial[blockIdx.x] = s4[0] + s4[1] + s4[2] + s4[3];
}

__global__ __launch_bounds__(256) void k_final(
    const float* __restrict__ accum, const float* __restrict__ partial,
    float* __restrict__ out) {
  __shared__ float s4[4];
  const int tid = threadIdx.x;
  float s = 0.f;
  for (int m = tid; m < NDBLK; m += 256) s += partial[m];
  s = wave_sum(s);
  if ((tid & 63) == 0) s4[tid >> 6] = s;
  __syncthreads();
  if (tid == 0) {
    float denom = s4[0] + s4[1] + s4[2] + s4[3];
    float possum = accum[1];
    float ccsum  = accum[2];
    float contrast = logf(denom) - possum / ((float)BS * TEMP);
    out[0] = contrast - 6.0f * ccsum / (float)BS;
  }
}

}  // namespace

extern "C" void kernel_launch(void* const* d_in, const int* in_sizes, int n_in,
                              void* d_out, int out_size, void* d_ws, size_t ws_size,
                              hipStream_t stream) {
  const float* queue  = (const float*)d_in[3];  // [2][QL][DIM]
  const float* proto  = (const float*)d_in[4];  // [K][DIM]
  const float* output = (const float*)d_in[5];  // [2*BS][K]
  const float* emb    = (const float*)d_in[6];  // [2*BS][DIM]
  float* ws = (float*)d_ws;
  ushort* M    = (ushort*)(ws + OFF_M);
  float* S     = ws + OFF_S;
  float* accum = ws + OFF_ACC;
  int* cnt     = (int*)(ws + OFF_CNT);
  int* offa    = (int*)(ws + OFF_OFFA);
  int* cur     = (int*)(ws + OFF_CUR);
  float* v     = ws + OFF_V;
  int* hardq   = (int*)(ws + OFF_HQ);
  int* negq    = (int*)(ws + OFF_NQ);
  float* logu  = ws + OFF_LOGU;
  int* bucket  = (int*)(ws + OFF_BUCKET);
  float* partial = ws + OFF_PART;
  ushort* cvt  = (ushort*)(ws + OFF_CVT);
  float* outc  = ws + OFF_OUTC;
  float* out   = (float*)d_out;

  // single fused zero: S(6KP) + accum(8) + cnt(3008) + offa(3072) + cur(3008)
  hipMemsetAsync(S, 0, (6 * KP + 8 + 3008 + 3072 + 3008) * sizeof(float), stream);

  {
    int n4q = 2 * QL * DIM / 4;
    k_convert<<<(n4q + 255) / 256, 256, 0, stream>>>(queue, cvt, n4q);
    int n4p = K * DIM / 4;
    k_convert<<<(n4p + 255) / 256, 256, 0, stream>>>(proto, cvt + (size_t)2 * QL * DIM, n4p);
  }

  for (int crop = 0; crop < 2; ++crop) {
    const float* ocrop = output + (size_t)crop * BS * K;
    const ushort* A = cvt + (size_t)crop * QL * DIM;
    const ushort* B = cvt + (size_t)2 * QL * DIM;
    float* S1 = S + (size_t)crop * 3 * KP;
    float* S2 = S1 + KP;
    float* S3 = S1 + 2 * KP;

    k_gemm<<<dim3((K + 127) / 128, QL / 128), 256, 0, stream>>>(A, B, M, S1);
    k_initsample<<<dim3((KP4 + 255) / 256, BS / 16), 256, 0, stream>>>(ocrop, M, S1);
    k_rowpass<<<NTOT, 256, 0, stream>>>(M, S1, v);
    k_colsum<<<dim3(3, NTOT / 32), 256, 0, stream>>>(M, v, S2);
    k_rowpass<<<NTOT, 256, 0, stream>>>(M, S2, v);
    k_colsum<<<dim3(3, NTOT / 32), 256, 0, stream>>>(M, v, S3);
    k_logu<<<3, 256, 0, stream>>>(S3, logu);
    if (crop == 0)
      k_stats<0><<<BS, 256, 0, stream>>>(output, logu, hardq, negq, accum);
    else
      k_stats<1><<<BS, 256, 0, stream>>>(output, logu, hardq, negq, accum);
  }

  k_normpos<<<BS, 256, 0, stream>>>(emb, outc, accum);
  k_hist<<<N2 / 256, 256, 0, stream>>>(hardq, cnt);
  k_scan<<<1, 256, 0, stream>>>(cnt, offa);
  k_scatter<<<N2 / 256, 256, 0, stream>>>(hardq, offa, cur, bucket);
  k_denom2<<<NDBLK, 256, 0, stream>>>(outc, negq, offa, bucket, partial);
  k_final<<<1, 256, 0, stream>>>(accum, partial, out);
}

// Round 7
// 332.594 us; speedup vs baseline: 2.2845x; 1.0267x over previous
//
#include <hip/hip_runtime.h>
#include <hip/hip_bf16.h>
#include <cstdint>

namespace {

constexpr int BS   = 2048;
constexpr int DIM  = 256;
constexpr int K    = 3000;
constexpr int K4   = K / 4;        // 750
constexpr int KP   = 3008;         // padded row stride (bf16 matrix)
constexpr int KP4  = KP / 4;       // 752
constexpr int QL   = 3840;
constexpr int NTOT = QL + BS;      // 5888
constexpr int N2   = 2 * BS;       // 4096
constexpr int NDBLK = N2 * 6 / 4;  // 6144
constexpr float TEMP = 0.2f;
constexpr float INV_EPS = 20.0f;
constexpr float KF = 3000.0f;

// ws layout (float indices)
constexpr size_t OFF_M    = 0;                              // NTOT*KP/2
constexpr size_t OFF_S    = OFF_M + (size_t)NTOT * KP / 2;  // 6*KP (S1..S3 x2 crops)
constexpr size_t OFF_ACC  = OFF_S + 6 * KP;                 // 8
constexpr size_t OFF_CNT  = OFF_ACC + 8;                    // 3008 ints
constexpr size_t OFF_OFFA = OFF_CNT + 3008;                 // 3072 ints
constexpr size_t OFF_CUR  = OFF_OFFA + 3072;                // 3008 ints
constexpr size_t OFF_V    = OFF_CUR + 3008;                 // NTOT
constexpr size_t OFF_HQ   = OFF_V + NTOT;                   // N2 ints
constexpr size_t OFF_NQ   = OFF_HQ + N2;                    // N2*6 ints
constexpr size_t OFF_LOGU = OFF_NQ + (size_t)N2 * 6;        // 3008
constexpr size_t OFF_BUCKET = OFF_LOGU + 3008;              // N2 ints
constexpr size_t OFF_PART = OFF_BUCKET + N2;                // NDBLK
constexpr size_t OFF_CVT  = ((OFF_PART + NDBLK + 15) / 16) * 16;
constexpr size_t OFF_OUTC = OFF_CVT;                        // reuse after GEMMs

using bf16x8 = __attribute__((ext_vector_type(8))) short;
using f32x4  = __attribute__((ext_vector_type(4))) float;
typedef unsigned int uint32;

__device__ __forceinline__ float wave_sum(float v) {
#pragma unroll
  for (int off = 32; off > 0; off >>= 1) v += __shfl_down(v, off, 64);
  return v;
}
__device__ __forceinline__ float wave_max_all(float v) {
#pragma unroll
  for (int off = 32; off > 0; off >>= 1) v = fmaxf(v, __shfl_xor(v, off, 64));
  return v;
}
__device__ __forceinline__ uint32 wave_min_u32_all(uint32 v) {
#pragma unroll
  for (int off = 32; off > 0; off >>= 1) {
    uint32 o = __shfl_xor(v, off, 64);
    v = o < v ? o : v;
  }
  return v;
}
__device__ __forceinline__ uint32 wave_max_u32(uint32 v) {
#pragma unroll
  for (int off = 32; off > 0; off >>= 1) {
    uint32 o = __shfl_down(v, off, 64);
    v = o > v ? o : v;
  }
  return v;
}
__device__ __forceinline__ uint32 fmono(float f) {
  uint32 u = __float_as_uint(f);
  return (u & 0x80000000u) ? ~u : (u | 0x80000000u);
}
__device__ __forceinline__ float bf2f(short s) {
  return __uint_as_float(((uint32)(unsigned short)s) << 16);
}
__device__ __forceinline__ ushort f2bf(float f) {
  __hip_bfloat16 b = __float2bfloat16(f);
  return *reinterpret_cast<ushort*>(&b);
}

// -------- f32 -> bf16 --------
__global__ __launch_bounds__(256) void k_convert(
    const float* __restrict__ x, ushort* __restrict__ hi, int n4) {
  int i = blockIdx.x * 256 + threadIdx.x;
  if (i >= n4) return;
  float4 v = reinterpret_cast<const float4*>(x)[i];
  ushort4 h;
  h.x = f2bf(v.x); h.y = f2bf(v.y); h.z = f2bf(v.z); h.w = f2bf(v.w);
  reinterpret_cast<ushort4*>(hi)[i] = h;
}

// -------- bf16 MFMA GEMM: M[m][n] = bf16(exp(dot/EPS)); S += colsum (v==1) --------
__global__ __launch_bounds__(256) void k_gemm(
    const ushort* __restrict__ A_g, const ushort* __restrict__ B_g,
    ushort* __restrict__ M, float* __restrict__ S) {
  __shared__ ushort Ah[128][40], Bh[128][40];
  const int tid  = threadIdx.x;
  const int bn0  = blockIdx.x * 128;
  const int bm0  = blockIdx.y * 128;
  const int wid  = tid >> 6, lane = tid & 63;
  const int wm0  = (wid >> 1) * 64, wn0 = (wid & 1) * 64;
  const int ln15 = lane & 15, lq = lane >> 4;
  const int lr   = tid >> 2;
  const int lc   = (tid & 3) * 8;

  f32x4 acc[4][4] = {};

  for (int kk = 0; kk < DIM; kk += 32) {
#pragma unroll
    for (int p = 0; p < 2; ++p) {
      int row = p * 64 + lr;
      size_t ga = (size_t)(bm0 + row) * DIM + kk + lc;
      int brow = bn0 + row; if (brow >= K) brow = K - 1;
      size_t gb = (size_t)brow * DIM + kk + lc;
      *reinterpret_cast<bf16x8*>(&Ah[row][lc]) = *reinterpret_cast<const bf16x8*>(&A_g[ga]);
      *reinterpret_cast<bf16x8*>(&Bh[row][lc]) = *reinterpret_cast<const bf16x8*>(&B_g[gb]);
    }
    __syncthreads();
    bf16x8 ah[4], bh[4];
#pragma unroll
    for (int i = 0; i < 4; ++i) {
      ah[i] = *reinterpret_cast<const bf16x8*>(&Ah[wm0 + i * 16 + ln15][lq * 8]);
      bh[i] = *reinterpret_cast<const bf16x8*>(&Bh[wn0 + i * 16 + ln15][lq * 8]);
    }
#pragma unroll
    for (int i = 0; i < 4; ++i)
#pragma unroll
      for (int j = 0; j < 4; ++j)
        acc[i][j] = __builtin_amdgcn_mfma_f32_16x16x32_bf16(ah[i], bh[j], acc[i][j], 0, 0, 0);
    __syncthreads();
  }

#pragma unroll
  for (int j = 0; j < 4; ++j) {
    int col = bn0 + wn0 + j * 16 + ln15;
    bool valid = col < K;
    bool inmat = col < KP;
    float csum = 0.f;
#pragma unroll
    for (int i = 0; i < 4; ++i) {
      int rowb = bm0 + wm0 + i * 16 + lq * 4;
#pragma unroll
      for (int r = 0; r < 4; ++r) {
        float q = valid ? __expf(acc[i][j][r] * INV_EPS) : 0.f;
        if (inmat) M[(size_t)(rowb + r) * KP + col] = f2bf(q);
        csum += q;
      }
    }
    csum += __shfl_xor(csum, 16, 64);
    csum += __shfl_xor(csum, 32, 64);
    if (lane < 16 && valid) atomicAdd(&S[col], csum);
  }
}

// -------- sample rows: exp -> bf16 matrix rows + v0-colsum into S --------
__global__ __launch_bounds__(256) void k_initsample(
    const float* __restrict__ outCrop, ushort* __restrict__ M, float* __restrict__ S) {
  int k4 = blockIdx.x * 256 + threadIdx.x;
  if (k4 >= KP4) return;
  bool pad = k4 >= K4;
  int r0 = blockIdx.y * 16;
  float ax = 0.f, ay = 0.f, az = 0.f, aw = 0.f;
  for (int rr = 0; rr < 16; ++rr) {
    int row = r0 + rr;
    ushort4 w = make_ushort4(0, 0, 0, 0);
    if (!pad) {
      float4 x = reinterpret_cast<const float4*>(outCrop + (size_t)row * K)[k4];
      float ex = __expf(x.x * INV_EPS), ey = __expf(x.y * INV_EPS),
            ez = __expf(x.z * INV_EPS), ew = __expf(x.w * INV_EPS);
      ax += ex; ay += ey; az += ez; aw += ew;
      w.x = f2bf(ex); w.y = f2bf(ey); w.z = f2bf(ez); w.w = f2bf(ew);
    }
    reinterpret_cast<ushort4*>(M + (size_t)(QL + row) * KP)[k4] = w;
  }
  if (!pad) {
    atomicAdd(&S[k4 * 4 + 0], ax);
    atomicAdd(&S[k4 * 4 + 1], ay);
    atomicAdd(&S[k4 * 4 + 2], az);
    atomicAdd(&S[k4 * 4 + 3], aw);
  }
}

// -------- rowpass: v[n] = 1/(NTOT * sum_k M[n][k]/(K*S_in[k])) --------
__global__ __launch_bounds__(256) void k_rowpass(
    const ushort* __restrict__ M, const float* __restrict__ S_in, float* __restrict__ v) {
  __shared__ float red[4];
  const int tid = threadIdx.x;
  const int n = blockIdx.x;
  const ushort* row = M + (size_t)n * KP;
  const int g1 = tid, g2 = tid + 256;
  const bool has2 = g2 < KP / 8;
  const bool pad2 = has2 && (g2 == 375);

  float ua[8], ub[8];
  {
    float4 s0 = reinterpret_cast<const float4*>(S_in)[g1 * 2];
    float4 s1 = reinterpret_cast<const float4*>(S_in)[g1 * 2 + 1];
    ua[0] = 1.0f / (KF * s0.x); ua[1] = 1.0f / (KF * s0.y);
    ua[2] = 1.0f / (KF * s0.z); ua[3] = 1.0f / (KF * s0.w);
    ua[4] = 1.0f / (KF * s1.x); ua[5] = 1.0f / (KF * s1.y);
    ua[6] = 1.0f / (KF * s1.z); ua[7] = 1.0f / (KF * s1.w);
  }
  if (has2 && !pad2) {
    float4 s0 = reinterpret_cast<const float4*>(S_in)[g2 * 2];
    float4 s1 = reinterpret_cast<const float4*>(S_in)[g2 * 2 + 1];
    ub[0] = 1.0f / (KF * s0.x); ub[1] = 1.0f / (KF * s0.y);
    ub[2] = 1.0f / (KF * s0.z); ub[3] = 1.0f / (KF * s0.w);
    ub[4] = 1.0f / (KF * s1.x); ub[5] = 1.0f / (KF * s1.y);
    ub[6] = 1.0f / (KF * s1.z); ub[7] = 1.0f / (KF * s1.w);
  } else {
#pragma unroll
    for (int e = 0; e < 8; ++e) ub[e] = 0.f;
  }

  float s = 0.f;
  {
    bf16x8 a = *reinterpret_cast<const bf16x8*>(&row[g1 * 8]);
#pragma unroll
    for (int e = 0; e < 8; ++e) s += bf2f(a[e]) * ua[e];
    if (has2) {
      bf16x8 c = *reinterpret_cast<const bf16x8*>(&row[g2 * 8]);
#pragma unroll
      for (int e = 0; e < 8; ++e) s += bf2f(c[e]) * ub[e];
    }
  }
  s = wave_sum(s);
  if ((tid & 63) == 0) red[tid >> 6] = s;
  __syncthreads();
  if (tid == 0) v[n] = 1.0f / ((float)NTOT * (red[0] + red[1] + red[2] + red[3]));
}

// -------- colsum: S_out[k] = sum_n M[n][k]*v[n] --------
__global__ __launch_bounds__(256) void k_colsum(
    const ushort* __restrict__ M, const float* __restrict__ v, float* __restrict__ S_out) {
  __shared__ float vsh[32];
  const int tid = threadIdx.x;
  const int g = blockIdx.x * 256 + tid;
  const int n0 = blockIdx.y * 32;
  if (tid < 32) vsh[tid] = v[n0 + tid];
  __syncthreads();
  if (g >= KP4) return;
  float c0 = 0.f, c1 = 0.f, c2 = 0.f, c3 = 0.f;
#pragma unroll 8
  for (int rr = 0; rr < 32; ++rr) {
    ushort4 m = reinterpret_cast<const ushort4*>(M + (size_t)(n0 + rr) * KP)[g];
    float vr = vsh[rr];
    c0 += bf2f((short)m.x) * vr;
    c1 += bf2f((short)m.y) * vr;
    c2 += bf2f((short)m.z) * vr;
    c3 += bf2f((short)m.w) * vr;
  }
  atomicAdd(&S_out[g * 4 + 0], c0);
  atomicAdd(&S_out[g * 4 + 1], c1);
  atomicAdd(&S_out[g * 4 + 2], c2);
  atomicAdd(&S_out[g * 4 + 3], c3);
}

// -------- logu[k] = -log(K * S3[k]) --------
__global__ __launch_bounds__(256) void k_logu(
    const float* __restrict__ S3, float* __restrict__ logu) {
  int k4 = blockIdx.x * 256 + threadIdx.x;
  if (k4 >= K4) return;
  float4 s = reinterpret_cast<const float4*>(S3)[k4];
  float4 r;
  r.x = -__logf(KF * s.x); r.y = -__logf(KF * s.y);
  r.z = -__logf(KF * s.z); r.w = -__logf(KF * s.w);
  reinterpret_cast<float4*>(logu)[k4] = r;
}

// -------- per sample row, ONE WAVE PER ROW (no barriers, no LDS):
//          hard_q, neg_q via 32-bit packed keys, crop-1 cc term --------
template <int CROP>
__global__ __launch_bounds__(256) void k_stats(
    const float* __restrict__ outputAll, const float* __restrict__ logu,
    int* __restrict__ hardq, int* __restrict__ negq, float* __restrict__ accum) {
  const int tid = threadIdx.x;
  const int lane = tid & 63, wid = tid >> 6;
  const int j = blockIdx.x * 4 + wid;
  const float4* orow4 = reinterpret_cast<const float4*>(outputAll + (size_t)(CROP * BS + j) * K);
  const float4* logu4 = reinterpret_cast<const float4*>(logu);

  // key layout: (fmono(r) & 0xFFFFF000) | k   (k = class index, < 4096)
  uint4 kb[12];
  float4 r4[12];            // only kept for CROP==1 (cc sums)
  uint32 lmin = 0xFFFFFFFFu;
  uint32 am = 0u;           // argmax key: trunc-mono | (4095 - k)

#pragma unroll
  for (int e = 0; e < 12; ++e) {
    const int g = lane + 64 * e;
    const bool valid = (e < 11) || (lane < 46);
    float4 o = valid ? orow4[g] : make_float4(0.f, 0.f, 0.f, 0.f);
    float4 l = valid ? logu4[g] : make_float4(0.f, 0.f, 0.f, 0.f);
    float4 rr;
    rr.x = fmaf(o.x, INV_EPS, l.x);
    rr.y = fmaf(o.y, INV_EPS, l.y);
    rr.z = fmaf(o.z, INV_EPS, l.z);
    rr.w = fmaf(o.w, INV_EPS, l.w);
    if (CROP == 1) r4[e] = rr;
    const int k0 = g * 4;
    uint32 mx0 = fmono(rr.x) & 0xFFFFF000u;
    uint32 mx1 = fmono(rr.y) & 0xFFFFF000u;
    uint32 mx2 = fmono(rr.z) & 0xFFFFF000u;
    uint32 mx3 = fmono(rr.w) & 0xFFFFF000u;
    uint4 kk;
    kk.x = valid ? (mx0 | (uint32)(k0 + 0)) : 0xFFFFFFFFu;
    kk.y = valid ? (mx1 | (uint32)(k0 + 1)) : 0xFFFFFFFFu;
    kk.z = valid ? (mx2 | (uint32)(k0 + 2)) : 0xFFFFFFFFu;
    kk.w = valid ? (mx3 | (uint32)(k0 + 3)) : 0xFFFFFFFFu;
    kb[e] = kk;
    lmin = kk.x < lmin ? kk.x : lmin;
    lmin = kk.y < lmin ? kk.y : lmin;
    lmin = kk.z < lmin ? kk.z : lmin;
    lmin = kk.w < lmin ? kk.w : lmin;
    if (valid) {
      uint32 a0 = mx0 | (uint32)(4095 - (k0 + 0));
      uint32 a1 = mx1 | (uint32)(4095 - (k0 + 1));
      uint32 a2 = mx2 | (uint32)(4095 - (k0 + 2));
      uint32 a3 = mx3 | (uint32)(4095 - (k0 + 3));
      uint32 m01 = a0 > a1 ? a0 : a1;
      uint32 m23 = a2 > a3 ? a2 : a3;
      uint32 mm = m01 > m23 ? m01 : m23;
      am = mm > am ? mm : am;
    }
  }

  // T8 = exact 8th smallest of the 64 lane-mins (upper bound on global 8th)
  uint32 t8;
  {
    uint32 c = lmin, wm = 0;
#pragma unroll
    for (int it = 0; it < 8; ++it) {
      wm = wave_min_u32_all(c);
      if (c == wm) c = 0xFFFFFFFFu;
    }
    t8 = wm;
  }

  // refill: per-lane sorted bottom-8 of keys <= t8 (rare inserts)
  uint32 cand[8];
#pragma unroll
  for (int t = 0; t < 8; ++t) cand[t] = 0xFFFFFFFFu;
#pragma unroll
  for (int e = 0; e < 12; ++e) {
    uint4 kk = kb[e];
    uint32 ks[4] = {kk.x, kk.y, kk.z, kk.w};
#pragma unroll
    for (int c = 0; c < 4; ++c) {
      uint32 key = ks[c];
      if (key <= t8 && key < cand[7]) {
        cand[7] = key;
#pragma unroll
        for (int t = 7; t > 0; --t)
          if (cand[t] < cand[t - 1]) { uint32 tmp = cand[t]; cand[t] = cand[t - 1]; cand[t - 1] = tmp; }
      }
    }
  }

  // wave knockout: exact bottom-8 ascending; record ranks 2..7
  uint32 res[6];
#pragma unroll
  for (int it = 0; it < 8; ++it) {
    uint32 head = cand[0];
    uint32 wm = wave_min_u32_all(head);
    if (it >= 2) res[it - 2] = wm;
    if (head == wm) {
      cand[0] = cand[1]; cand[1] = cand[2]; cand[2] = cand[3]; cand[3] = cand[4];
      cand[4] = cand[5]; cand[5] = cand[6]; cand[6] = cand[7]; cand[7] = 0xFFFFFFFFu;
    }
  }

  am = wave_max_u32(am);
  if (lane == 0) {
    hardq[CROP * BS + j] = 4095 - (int)(am & 0xFFFu);
#pragma unroll
    for (int t = 0; t < 6; ++t)
      negq[(size_t)(CROP * BS + j) * 6 + t] = (int)(res[t] & 0xFFFu);
  }

  if (CROP == 1) {
    const float4* xrow4 = reinterpret_cast<const float4*>(outputAll + (size_t)j * K);
    float4 x4[12];
    float mx = -3.4e38f;
#pragma unroll
    for (int e = 0; e < 12; ++e) {
      const bool valid = (e < 11) || (lane < 46);
      float4 x = valid ? xrow4[lane + 64 * e]
                       : make_float4(-3.4e38f, -3.4e38f, -3.4e38f, -3.4e38f);
      x4[e] = x;
      mx = fmaxf(mx, fmaxf(fmaxf(x.x, x.y), fmaxf(x.z, x.w)));
    }
    mx = wave_max_all(mx);
    float sk = 0.f, skx = 0.f, se = 0.f;
#pragma unroll
    for (int e = 0; e < 12; ++e) {
      const bool valid = (e < 11) || (lane < 46);
      if (valid) {
        float4 rr = r4[e];
        float4 x = x4[e];
        float q;
        q = __expf(rr.x); sk += q; skx += q * x.x; se += __expf((x.x - mx) * 5.0f);
        q = __expf(rr.y); sk += q; skx += q * x.y; se += __expf((x.y - mx) * 5.0f);
        q = __expf(rr.z); sk += q; skx += q * x.z; se += __expf((x.z - mx) * 5.0f);
        q = __expf(rr.w); sk += q; skx += q * x.w; se += __expf((x.w - mx) * 5.0f);
      }
    }
    sk = wave_sum(sk); skx = wave_sum(skx); se = wave_sum(se);
    if (lane == 0) {
      float lse = mx * 5.0f + __logf(se);
      atomicAdd(&accum[2], skx * 5.0f / sk - lse);
    }
  }
}

// -------- normalize both pair rows + pos dot --------
__global__ __launch_bounds__(256) void k_normpos(
    const float* __restrict__ emb, float* __restrict__ outc, float* __restrict__ accum) {
  __shared__ float sa[4], sb[4], sd[4];
  __shared__ float na, nb;
  const int j = blockIdx.x, t = threadIdx.x;
  float za = emb[(size_t)(BS + j) * DIM + t] / TEMP;  // -> outc[j]
  float zb = emb[(size_t)j * DIM + t] / TEMP;         // -> outc[BS+j]
  float ra = wave_sum(za * za);
  float rb = wave_sum(zb * zb);
  if ((t & 63) == 0) { sa[t >> 6] = ra; sb[t >> 6] = rb; }
  __syncthreads();
  if (t == 0) {
    na = sqrtf(sa[0] + sa[1] + sa[2] + sa[3]);
    nb = sqrtf(sb[0] + sb[1] + sb[2] + sb[3]);
  }
  __syncthreads();
  float oa = za / na, ob = zb / nb;
  outc[(size_t)j * DIM + t] = oa;
  outc[(size_t)(BS + j) * DIM + t] = ob;
  float d = wave_sum(oa * ob);
  if ((t & 63) == 0) sd[t >> 6] = d;
  __syncthreads();
  if (t == 0) atomicAdd(&accum[1], sd[0] + sd[1] + sd[2] + sd[3]);
}

// -------- denom via class histogram --------
__global__ __launch_bounds__(256) void k_hist(
    const int* __restrict__ hardq, int* __restrict__ cnt) {
  int j = blockIdx.x * 256 + threadIdx.x;
  atomicAdd(&cnt[hardq[j]], 1);
}

__global__ __launch_bounds__(256) void k_scan(
    const int* __restrict__ cnt, int* __restrict__ offa) {
  __shared__ int wsum[4];
  __shared__ int wpre[4];
  const int tid = threadIdx.x;
  const int lane = tid & 63, wid = tid >> 6;
  const int base = tid * 12;
  int loc[12];
  int s = 0;
#pragma unroll
  for (int t = 0; t < 12; ++t) {
    int idx = base + t;
    int cv = (idx < K) ? cnt[idx] : 0;
    loc[t] = cv; s += cv;
  }
  int vincl = s;
#pragma unroll
  for (int d = 1; d < 64; d <<= 1) {
    int t = __shfl_up(vincl, d, 64);
    if (lane >= d) vincl += t;
  }
  if (lane == 63) wsum[wid] = vincl;
  __syncthreads();
  if (tid == 0) {
    int r = 0;
#pragma unroll
    for (int w = 0; w < 4; ++w) { wpre[w] = r; r += wsum[w]; }
  }
  __syncthreads();
  int run = vincl - s + wpre[wid];
#pragma unroll
  for (int t = 0; t < 12; ++t) {
    int idx = base + t;
    if (idx < K) { offa[idx] = run; run += loc[t]; }
  }
  if (tid == 255) offa[K] = run;
}

__global__ __launch_bounds__(256) void k_scatter(
    const int* __restrict__ hardq, const int* __restrict__ offa,
    int* __restrict__ cur, int* __restrict__ bucket) {
  int j = blockIdx.x * 256 + threadIdx.x;
  int c = hardq[j];
  int p = atomicAdd(&cur[c], 1);
  bucket[offa[c] + p] = j;
}

__global__ __launch_bounds__(256) void k_denom2(
    const float* __restrict__ outc, const int* __restrict__ negq,
    const int* __restrict__ offa, const int* __restrict__ bucket,
    float* __restrict__ partial) {
  __shared__ float s4[4];
  const int tid = threadIdx.x;
  const int wid = tid >> 6, lane = tid & 63;
  const int task = blockIdx.x * 4 + wid;
  const int i = task / 6, slot = task - i * 6;
  const int c = negq[i * 6 + slot];
  const int lo = offa[c];
  const int n = offa[c + 1] - lo;
  float acc = 0.f;
  if (n > 0) {
    const float4 a = reinterpret_cast<const float4*>(outc + (size_t)i * DIM)[lane];
    for (int m = 0; m < n; ++m) {
      int j = bucket[lo + m];
      if (j == i) continue;
      const float4 b = reinterpret_cast<const float4*>(outc + (size_t)j * DIM)[lane];
      float d = a.x * b.x + a.y * b.y + a.z * b.z + a.w * b.w;
      d = wave_sum(d);
      if (lane == 0) acc += __expf(d * 5.0f);
    }
  }
  if (lane == 0) s4[wid] = acc;
  __syncthreads();
  if (tid == 0) partial[blockIdx.x] = s4[0] + s4[1] + s4[2] + s4[3];
}

__global__ __launch_bounds__(256) void k_final(
    const float* __restrict__ accum, const float* __restrict__ partial,
    float* __restrict__ out) {
  __shared__ float s4[4];
  const int tid = threadIdx.x;
  float s = 0.f;
  for (int m = tid; m < NDBLK; m += 256) s += partial[m];
  s = wave_sum(s);
  if ((tid & 63) == 0) s4[tid >> 6] = s;
  __syncthreads();
  if (tid == 0) {
    float denom = s4[0] + s4[1] + s4[2] + s4[3];
    float possum = accum[1];
    float ccsum  = accum[2];
    float contrast = logf(denom) - possum / ((float)BS * TEMP);
    out[0] = contrast - 6.0f * ccsum / (float)BS;
  }
}

}  // namespace

extern "C" void kernel_launch(void* const* d_in, const int* in_sizes, int n_in,
                              void* d_out, int out_size, void* d_ws, size_t ws_size,
                              hipStream_t stream) {
  const float* queue  = (const float*)d_in[3];  // [2][QL][DIM]
  const float* proto  = (const float*)d_in[4];  // [K][DIM]
  const float* output = (const float*)d_in[5];  // [2*BS][K]
  const float* emb    = (const float*)d_in[6];  // [2*BS][DIM]
  float* ws = (float*)d_ws;
  ushort* M    = (ushort*)(ws + OFF_M);
  float* S     = ws + OFF_S;
  float* accum = ws + OFF_ACC;
  int* cnt     = (int*)(ws + OFF_CNT);
  int* offa    = (int*)(ws + OFF_OFFA);
  int* cur     = (int*)(ws + OFF_CUR);
  float* v     = ws + OFF_V;
  int* hardq   = (int*)(ws + OFF_HQ);
  int* negq    = (int*)(ws + OFF_NQ);
  float* logu  = ws + OFF_LOGU;
  int* bucket  = (int*)(ws + OFF_BUCKET);
  float* partial = ws + OFF_PART;
  ushort* cvt  = (ushort*)(ws + OFF_CVT);
  float* outc  = ws + OFF_OUTC;
  float* out   = (float*)d_out;

  // single fused zero: S(6KP) + accum(8) + cnt(3008) + offa(3072) + cur(3008)
  hipMemsetAsync(S, 0, (6 * KP + 8 + 3008 + 3072 + 3008) * sizeof(float), stream);

  {
    int n4q = 2 * QL * DIM / 4;
    k_convert<<<(n4q + 255) / 256, 256, 0, stream>>>(queue, cvt, n4q);
    int n4p = K * DIM / 4;
    k_convert<<<(n4p + 255) / 256, 256, 0, stream>>>(proto, cvt + (size_t)2 * QL * DIM, n4p);
  }

  for (int crop = 0; crop < 2; ++crop) {
    const float* ocrop = output + (size_t)crop * BS * K;
    const ushort* A = cvt + (size_t)crop * QL * DIM;
    const ushort* B = cvt + (size_t)2 * QL * DIM;
    float* S1 = S + (size_t)crop * 3 * KP;
    float* S2 = S1 + KP;
    float* S3 = S1 + 2 * KP;

    k_gemm<<<dim3((K + 127) / 128, QL / 128), 256, 0, stream>>>(A, B, M, S1);
    k_initsample<<<dim3((KP4 + 255) / 256, BS / 16), 256, 0, stream>>>(ocrop, M, S1);
    k_rowpass<<<NTOT, 256, 0, stream>>>(M, S1, v);
    k_colsum<<<dim3(3, NTOT / 32), 256, 0, stream>>>(M, v, S2);
    k_rowpass<<<NTOT, 256, 0, stream>>>(M, S2, v);
    k_colsum<<<dim3(3, NTOT / 32), 256, 0, stream>>>(M, v, S3);
    k_logu<<<3, 256, 0, stream>>>(S3, logu);
    if (crop == 0)
      k_stats<0><<<BS / 4, 256, 0, stream>>>(output, logu, hardq, negq, accum);
    else
      k_stats<1><<<BS / 4, 256, 0, stream>>>(output, logu, hardq, negq, accum);
  }

  k_normpos<<<BS, 256, 0, stream>>>(emb, outc, accum);
  k_hist<<<N2 / 256, 256, 0, stream>>>(hardq, cnt);
  k_scan<<<1, 256, 0, stream>>>(cnt, offa);
  k_scatter<<<N2 / 256, 256, 0, stream>>>(hardq, offa, cur, bucket);
  k_denom2<<<NDBLK, 256, 0, stream>>>(outc, negq, offa, bucket, partial);
  k_final<<<1, 256, 0, stream>>>(accum, partial, out);
}